// Round 26
// baseline (399.534 us; speedup 1.0000x reference)
//
#include <hip/hip_runtime.h>

// Problem constants (fixed by the reference)
constexpr int B_  = 4;
constexpr int N_  = 2048;
constexpr int HID_ = 1024;
constexpr int NH_ = 4;
constexpr int DK_ = 256;
constexpr int DV_ = 512;
constexpr int C_  = 64;     // chunk size
constexpr int NC_ = 32;     // chunks per sequence
constexpr int M_  = B_ * N_;  // 8192 rows
constexpr int NSEG_ = 4;    // scan segments
constexpr int CSEG_ = NC_ / NSEG_;  // 8 chunks per segment
constexpr int QW_ = 6144;   // fused q|k|v|g row width

using ushort_t = unsigned short;
typedef __attribute__((ext_vector_type(8))) short bf16x8;
typedef __attribute__((ext_vector_type(4))) float f32x4;

__device__ __forceinline__ ushort_t f2bf(float f) {
  union { float fv; unsigned u; } v; v.fv = f;
  unsigned r = v.u + 0x7FFFu + ((v.u >> 16) & 1u);   // round-to-nearest-even
  return (ushort_t)(r >> 16);
}
__device__ __forceinline__ float bf2f(ushort_t u) {
  union { unsigned u; float f; } v; v.u = ((unsigned)u) << 16; return v.f;
}

__device__ __forceinline__ void gload_lds16(const void* g, void* l) {
  __builtin_amdgcn_global_load_lds(
      (const __attribute__((address_space(1))) unsigned int*)g,
      (__attribute__((address_space(3))) unsigned int*)l, 16, 0, 0);
}

__device__ __forceinline__ f32x4 mfma16(bf16x8 a, bf16x8 b, f32x4 c) {
  return __builtin_amdgcn_mfma_f32_16x16x32_bf16(a, b, c, 0, 0, 0);
}

// ---------------------------------------------------------------------------
// bf16 MFMA GEMM, TRIPLE-buffered BK=32 counted-vmcnt pipeline (R23-proven).
// 256x128 tile, 512 thr = 8 waves.  LDS 72 KB -> 2 blocks/CU.
// ---------------------------------------------------------------------------
#define GSTAGE_A(G, Kd, kt32, dst)                                             \
  do {                                                                         \
    _Pragma("unroll")                                                          \
    for (int j = 0; j < 2; ++j) {                                              \
      const int cb = j * 8 + wave;                /* 0..15 */                  \
      const int srow = (cb * 64 + lane) >> 2;     /* 0..255 */                 \
      gload_lds16((G) + (size_t)srow * (Kd) + (kt32) * 32 + kp,                \
                  (dst) + cb * 512);                                           \
    }                                                                          \
  } while (0)
#define GSTAGE_B(G, Kd, kt32, dst)                                             \
  do {                                                                         \
    const int cb = wave;                          /* 0..7 */                   \
    const int srow = (cb * 64 + lane) >> 2;       /* 0..127 */                 \
    gload_lds16((G) + (size_t)srow * (Kd) + (kt32) * 32 + kp,                  \
                (dst) + cb * 512);                                             \
  } while (0)

template<bool BF16OUT>
__global__ __launch_bounds__(512) void gemm_mfma(
    const ushort_t* __restrict__ A, const ushort_t* __restrict__ BT,
    void* __restrict__ CV, int N, int K) {
  __shared__ ushort_t Ah[3][256 * 32];   // 48 KB
  __shared__ ushort_t Bh[3][128 * 32];   // 24 KB
  const int tid = threadIdx.x;
  const int wave = tid >> 6, lane = tid & 63;
  const size_t brow = (size_t)blockIdx.y * 256;
  const size_t bcol = (size_t)blockIdx.x * 128;
  const int wr = (wave >> 1) * 64, wc = (wave & 1) * 64;
  const int frow = lane & 15;
  const int fko  = ((lane >> 4) ^ (frow & 3)) * 8;          // swizzled read k-off
  const int kp   = (((lane & 3) ^ ((lane >> 2) & 3)) * 8);  // inverse-swz src k-off

  f32x4 acc[4][4];
#pragma unroll
  for (int m = 0; m < 4; ++m)
#pragma unroll
    for (int n = 0; n < 4; ++n) acc[m][n] = f32x4{0.f, 0.f, 0.f, 0.f};

  const ushort_t* Ag = A + brow * K;
  const ushort_t* Bg = BT + bcol * K;
  const int NT = K >> 5;                 // K-tiles of 32

  GSTAGE_A(Ag, K, 0, Ah[0]);
  GSTAGE_B(Bg, K, 0, Bh[0]);
  GSTAGE_A(Ag, K, 1, Ah[1]);
  GSTAGE_B(Bg, K, 1, Bh[1]);
  asm volatile("s_waitcnt vmcnt(3)" ::: "memory");
  __builtin_amdgcn_s_barrier();

  int rb = 0, sb = 2;                    // read buf, stage buf
  bf16x8 af[4], bfr[4];
  for (int kt = 0; kt < NT; ++kt) {
#pragma unroll
    for (int m = 0; m < 4; ++m)
      af[m] = *(const bf16x8*)(&Ah[rb][(wr + m * 16 + frow) * 32 + fko]);
#pragma unroll
    for (int n = 0; n < 4; ++n)
      bfr[n] = *(const bf16x8*)(&Bh[rb][(wc + n * 16 + frow) * 32 + fko]);
    if (kt + 2 < NT) {
      GSTAGE_A(Ag, K, kt + 2, Ah[sb]);
      GSTAGE_B(Bg, K, kt + 2, Bh[sb]);
    }
#pragma unroll
    for (int m = 0; m < 4; ++m)
#pragma unroll
      for (int n = 0; n < 4; ++n) acc[m][n] = mfma16(af[m], bfr[n], acc[m][n]);
    if (kt + 1 < NT) {
      if (kt + 2 < NT) asm volatile("s_waitcnt vmcnt(3)" ::: "memory");
      else             asm volatile("s_waitcnt vmcnt(0)" ::: "memory");
      __builtin_amdgcn_s_barrier();
    }
    rb = (rb == 2) ? 0 : rb + 1;
    sb = (sb == 2) ? 0 : sb + 1;
  }

  const int crow = (lane >> 4) * 4;
  const int ccol = lane & 15;
#pragma unroll
  for (int m = 0; m < 4; ++m)
#pragma unroll
    for (int n = 0; n < 4; ++n) {
      const size_t base = (brow + wr + m * 16 + crow) * (size_t)N + (bcol + wc + n * 16 + ccol);
      if constexpr (BF16OUT) {
        ushort_t* Out = (ushort_t*)CV;
#pragma unroll
        for (int j = 0; j < 4; ++j) Out[base + (size_t)j * N] = f2bf(acc[m][n][j]);
      } else {
        float* Out = (float*)CV;
#pragma unroll
        for (int j = 0; j < 4; ++j) Out[base + (size_t)j * N] = acc[m][n][j];
      }
    }
}

// ---------------------------------------------------------------------------
// Fused prologue: 5 weight transposes + {x->bf16 AND gk} per row.
// ---------------------------------------------------------------------------
__global__ __launch_bounds__(256) void prep_all(
    const float* __restrict__ Wq, const float* __restrict__ Wk,
    const float* __restrict__ Wv, const float* __restrict__ Wg,
    const float* __restrict__ Wo, const float* __restrict__ x,
    const float* __restrict__ Wgk, const float* __restrict__ bgk,
    ushort_t* __restrict__ WqT, ushort_t* __restrict__ WkT,
    ushort_t* __restrict__ WvT, ushort_t* __restrict__ WgT,
    ushort_t* __restrict__ WoT, ushort_t* __restrict__ xb,
    float* __restrict__ gkbuf) {
  __shared__ float tile[32][33];
  __shared__ float4 red4[256];
  const int blk = blockIdx.x;
  const int tid = threadIdx.x;
  if (blk >= 8192) {   // x -> bf16 + gk: one row (1024 floats) per block
    const int row = blk - 8192;
    const size_t i = ((size_t)row * 1024) + tid * 4;
    float4 v = *(const float4*)(x + i);
    ushort4 r;
    r.x = f2bf(v.x); r.y = f2bf(v.y); r.z = f2bf(v.z); r.w = f2bf(v.w);
    *(ushort4*)(xb + i) = r;
    float4 p = {0.f, 0.f, 0.f, 0.f};
    const float4* wg4 = (const float4*)Wgk;   // [1024] rows of 4
    const float xv[4] = {v.x, v.y, v.z, v.w};
#pragma unroll
    for (int j = 0; j < 4; ++j) {
      float4 wg = wg4[tid * 4 + j];
      p.x += xv[j] * wg.x; p.y += xv[j] * wg.y;
      p.z += xv[j] * wg.z; p.w += xv[j] * wg.w;
    }
    red4[tid] = p;
    __syncthreads();
    for (int off2 = 128; off2; off2 >>= 1) {
      if (tid < off2) {
        float4 a = red4[tid], b4 = red4[tid + off2];
        a.x += b4.x; a.y += b4.y; a.z += b4.z; a.w += b4.w;
        red4[tid] = a;
      }
      __syncthreads();
    }
    if (tid < 4) {
      const float z  = (&red4[0].x)[tid] + bgk[tid];
      const float ls = fminf(z, 0.f) - log1pf(expf(-fabsf(z)));
      const int b = row >> 11, n = row & 2047;
      gkbuf[((size_t)(b * NH_ + tid)) * N_ + n] = ls * (1.0f / 16.0f);
    }
    return;
  }
  const float* W; ushort_t* WT; int K, Nn, gxw, local;
  if (blk < 1024)      { W = Wq; WT = WqT; K = 1024; Nn = 1024; gxw = 32; local = blk; }
  else if (blk < 2048) { W = Wk; WT = WkT; K = 1024; Nn = 1024; gxw = 32; local = blk - 1024; }
  else if (blk < 4096) { W = Wv; WT = WvT; K = 1024; Nn = 2048; gxw = 64; local = blk - 2048; }
  else if (blk < 6144) { W = Wg; WT = WgT; K = 1024; Nn = 2048; gxw = 64; local = blk - 4096; }
  else                 { W = Wo; WT = WoT; K = 2048; Nn = 1024; gxw = 32; local = blk - 6144; }
  const int n0 = (local % gxw) * 32, k0 = (local / gxw) * 32;
  const int tx = tid & 31, ty = tid >> 5;
#pragma unroll
  for (int i = 0; i < 32; i += 8)
    tile[ty + i][tx] = W[(size_t)(k0 + ty + i) * Nn + n0 + tx];
  __syncthreads();
#pragma unroll
  for (int i = 0; i < 32; i += 8)
    WT[(size_t)(n0 + ty + i) * K + k0 + tx] = f2bf(tile[tx][ty + i]);
}

// ---------------------------------------------------------------------------
// Fused post-qkv stage (reads fused qkvg16 [8192][6144]).  CUMSUM FUSED:
// gc is chunk-local (reference cumsums within each 64-chunk), so each branch
// computes its chunk's inclusive prefix from gk via a left fold in increasing
// order — bit-identical to the old serial cumsum kernel.  pack_kT (one block
// per (bh,c)) additionally writes gc to global for scan/correct.
//   [0,512) a_mfma | [512,1024) pack_kT | [1024,2048) pack_vT |
//   [2048,6144) pack_q16 (reads gc?  no — computes its own factor from gk)
// NOTE: pack_q16 needs gc[bh,n] per element row; it runs concurrently with
// pack_kT so it cannot read global gc.  It computes the prefix locally from
// gk (same left fold over the row's chunk) — bit-identical values.
// ---------------------------------------------------------------------------
__global__ __launch_bounds__(256) void post_qkv(
    const ushort_t* __restrict__ qkvg16, const float* __restrict__ gk,
    float* __restrict__ gc,
    ushort_t* __restrict__ Abuf, ushort_t* __restrict__ kT,
    ushort_t* __restrict__ vT, ushort_t* __restrict__ q16) {
  __shared__ __align__(16) char smem[256 * 68 * 2 + 512];
  const int gblk = blockIdx.x;
  const int tid = threadIdx.x;

  if (gblk < 512) {               // ---------------- a_mfma
    const int blk = gblk;
    const int bh  = blk >> 5, c = blk & 31;
    const int b   = bh >> 2, h = bh & 3;
    float* gks = (float*)smem;          // [64] raw gk
    float* gcs = (float*)smem + 64;     // [64] prefix
    const int w = tid >> 6, l = tid & 63;
    const int frow = l & 15, fgrp = l >> 4;
    if (tid < 64) gks[tid] = gk[(size_t)bh * N_ + c * C_ + tid];
    __syncthreads();
    if (tid < 64) {   // left-fold prefix, increasing order (== serial cumsum)
      float s = 0.f;
      for (int i = 0; i <= tid; ++i) s += gks[i];
      gcs[tid] = s;
    }
    __syncthreads();

    const size_t rbase = (size_t)(b * N_ + c * C_);
    bf16x8 aqr[8];
#pragma unroll
    for (int kk = 0; kk < 8; ++kk)
      aqr[kk] = *(const bf16x8*)(qkvg16 + (rbase + w * 16 + frow) * QW_ +
                                 h * 256 + kk * 32 + fgrp * 8);

    ushort_t* ab = Abuf + (size_t)blk * 4096;
    const float scl = 0.0625f;
#pragma unroll
    for (int n = 0; n < 4; ++n) {
      f32x4 acc = f32x4{0.f, 0.f, 0.f, 0.f};
#pragma unroll
      for (int kk = 0; kk < 8; ++kk) {
        bf16x8 bk = *(const bf16x8*)(qkvg16 + (rbase + n * 16 + frow) * QW_ +
                                     1024 + h * 256 + kk * 32 + fgrp * 8);
        acc = mfma16(aqr[kk], bk, acc);
      }
      const int s = n * 16 + frow;
      const float gcss = gcs[s];
#pragma unroll
      for (int j = 0; j < 4; ++j) {
        const int t = w * 16 + fgrp * 4 + j;
        const float val = (s <= t) ? acc[j] * scl * expf(gcs[t] - gcss) : 0.f;
        ab[(size_t)t * 64 + s] = f2bf(val);
      }
    }
  } else if (gblk < 1024) {       // ---------------- pack_kT (+ writes gc)
    const int blk = gblk - 512;
    const int bh = blk >> 5, c = blk & 31;
    const int b = bh >> 2, h = bh & 3;
    ushort_t (*kl)[68] = (ushort_t (*)[68])smem;           // [256][68]
    float* gks = (float*)(smem + 256 * 68 * 2);            // [64]
    float* fk  = gks;                                      // reused after gc
    __shared__ float gcl[64];
    if (tid < 64) gks[tid] = gk[(size_t)bh * N_ + c * C_ + tid];
    __syncthreads();
    if (tid < 64) {   // left-fold prefix (== serial cumsum), publish to global
      float s = 0.f;
      for (int i = 0; i <= tid; ++i) s += gks[i];
      gcl[tid] = s;
      gc[(size_t)bh * N_ + c * C_ + tid] = s;
    }
    __syncthreads();
    if (tid < 64) fk[tid] = expf(gcl[63] - gcl[tid]);
    __syncthreads();
    const ushort_t* kb = qkvg16 + (size_t)(b * N_ + c * C_) * QW_ + 1024 + h * 256;
    for (int it = 0; it < 8; ++it) {
      const int e = it * 256 + tid;
      const int t = e >> 5, d8 = (e & 31) * 8;
      bf16x8 kv = *(const bf16x8*)(kb + (size_t)t * QW_ + d8);
      const float f = fk[t];
#pragma unroll
      for (int j = 0; j < 8; ++j) kl[d8 + j][t] = f2bf(bf2f((ushort_t)kv[j]) * f);
    }
    __syncthreads();
    ushort_t* out = kT + (size_t)blk * 16384;
    for (int it = 0; it < 8; ++it) {
      const int e = it * 256 + tid;
      const int d = e >> 3, t8 = (e & 7) * 8;
      ushort4 lo, hi;
      lo.x = kl[d][t8 + 0]; lo.y = kl[d][t8 + 1]; lo.z = kl[d][t8 + 2]; lo.w = kl[d][t8 + 3];
      hi.x = kl[d][t8 + 4]; hi.y = kl[d][t8 + 5]; hi.z = kl[d][t8 + 6]; hi.w = kl[d][t8 + 7];
      *(ushort4*)(out + (size_t)d * 64 + t8)     = lo;
      *(ushort4*)(out + (size_t)d * 64 + t8 + 4) = hi;
    }
  } else if (gblk < 2048) {       // ---------------- pack_vT
    const int blk = gblk - 1024;
    const int eh = blk & 1, c = (blk >> 1) & 31, bh = blk >> 6;
    const int b = bh >> 2, h = bh & 3;
    ushort_t (*vl)[68] = (ushort_t (*)[68])smem;           // [256][68]
    const ushort_t* vb = qkvg16 + (size_t)(b * N_ + c * C_) * QW_ + 2048 + h * 512 + eh * 256;
    for (int it = 0; it < 8; ++it) {
      const int e = it * 256 + tid;
      const int s = e >> 5, c8 = (e & 31) * 8;
      bf16x8 val = *(const bf16x8*)(vb + (size_t)s * QW_ + c8);
#pragma unroll
      for (int j = 0; j < 8; ++j) vl[c8 + j][s] = (ushort_t)val[j];
    }
    __syncthreads();
    ushort_t* out = vT + (size_t)bh * 512 * 2048 + (size_t)(eh * 256) * 2048 + c * C_;
    for (int it = 0; it < 8; ++it) {
      const int e = it * 256 + tid;
      const int r = e >> 3, t8 = (e & 7) * 8;
      ushort4 lo, hi;
      lo.x = vl[r][t8 + 0]; lo.y = vl[r][t8 + 1]; lo.z = vl[r][t8 + 2]; lo.w = vl[r][t8 + 3];
      hi.x = vl[r][t8 + 4]; hi.y = vl[r][t8 + 5]; hi.z = vl[r][t8 + 6]; hi.w = vl[r][t8 + 7];
      *(ushort4*)(out + (size_t)r * 2048 + t8)     = lo;
      *(ushort4*)(out + (size_t)r * 2048 + t8 + 4) = hi;
    }
  } else {                        // ---------------- pack_q16 (local prefix)
    // block covers 8 rows of 2 half-rows?  Layout: 4096 blocks, each 256 thr
    // * 8 elems = 2048 elems = 2 rows of q (1024 each).  Rows r0 = 2*(gblk-2048),
    // r0+1.  Each 128-thread half handles one row; its chunk prefix is
    // computed from gk by a left fold at the needed position.
    const size_t i8 = ((size_t)(gblk - 2048) * 256 + tid) * 8;   // < M*1024
    const int row = (int)(i8 >> 10);
    const int b = row >> 11, n = row & 2047;
    const int col = (int)(i8 & 1023);
    const int h = col >> 8;
    // left-fold prefix of gk over this row's chunk up to position n%64
    const int cbase = n & ~63, tpos = n & 63;
    const float* gkr = gk + (size_t)(b * NH_ + h) * N_ + cbase;
    float s = 0.f;
    for (int i = 0; i <= tpos; ++i) s += gkr[i];
    const float f = 0.0625f * expf(s);
    bf16x8 v = *(const bf16x8*)(qkvg16 + (size_t)row * QW_ + col);
    ushort_t r[8];
#pragma unroll
    for (int j = 0; j < 8; ++j) r[j] = f2bf(bf2f((ushort_t)v[j]) * f);
    *(bf16x8*)(q16 + i8) = *(bf16x8*)r;
  }
}

// ---------------------------------------------------------------------------
// Segmented MFMA chunk scan, EBLK=64, cross-barrier prefetch of aq+bv+aa.
// SINGLE S^T buffer (33.8 KB LDS -> 4 WG/CU) with 2 barriers/chunk.
// grid = (16 bh, 8 vblk, 4 seg), wgid%8 = bh%8 (XCD affinity).
// ---------------------------------------------------------------------------
#define LOAD_AQ(cc, dst)                                                       \
  do {                                                                         \
    _Pragma("unroll")                                                          \
    for (int kk = 0; kk < 8; ++kk)                                             \
      dst[kk] = *(const bf16x8*)(qbase + (size_t)((cc) * C_ + w * 16 + frow) * 1024 + \
                                 kk * 32 + fgrp * 8);                          \
  } while (0)
#define LOAD_BV(cc, dst)                                                       \
  do {                                                                         \
    _Pragma("unroll")                                                          \
    for (int kt = 0; kt < 2; ++kt)                                             \
      _Pragma("unroll")                                                        \
      for (int n = 0; n < 4; ++n)                                              \
        dst[kt][n] = *(const bf16x8*)(vbase + (size_t)(n * 16 + frow) * 2048 + \
                                      (cc) * C_ + kt * 32 + fgrp * 8);         \
  } while (0)
#define LOAD_AA(cc, dst)                                                       \
  do {                                                                         \
    _Pragma("unroll")                                                          \
    for (int kt = 0; kt < 2; ++kt)                                             \
      dst[kt] = *(const bf16x8*)(abase + (size_t)(cc) * 4096 +                 \
                                 (w * 16 + frow) * 64 + kt * 32 + fgrp * 8);   \
  } while (0)

__global__ __launch_bounds__(256) void scan_mfma(
    const ushort_t* __restrict__ q16,   // [8192][1024] pre-scaled bf16
    const ushort_t* __restrict__ kT,    // [bh][c][256][64] decayed bf16
    const ushort_t* __restrict__ vT,    // [bh][512][2048] bf16
    const ushort_t* __restrict__ ab,    // [bh*32+c][64][64] bf16
    const float*    __restrict__ gc,
    ushort_t* __restrict__ o,           // [8192][2048] bf16 (intra-segment part)
    float*    __restrict__ U) {         // [bh][seg 0..2][256][512] fp32
  const int bh = blockIdx.x, vblk = blockIdx.y, sg = blockIdx.z;
  const int b = bh >> 2, h = bh & 3;
  const int e0 = vblk * 64;
  const int c0 = sg * CSEG_;
  __shared__ ushort_t sbt[64][264];     // S^T bf16 single buffer (33.8 KB)
  __shared__ float egts[NC_];
  const int tid = threadIdx.x;
  const int w = tid >> 6, l = tid & 63;
  const int frow = l & 15, fgrp = l >> 4;

  for (int i = tid; i < 64 * 264 / 2; i += 256) ((unsigned*)&sbt[0][0])[i] = 0u;
  if (tid < NC_) egts[tid] = expf(gc[(size_t)bh * N_ + tid * C_ + 63]);
  f32x4 s_acc[4][4];
#pragma unroll
  for (int sm = 0; sm < 4; ++sm)
#pragma unroll
    for (int sn = 0; sn < 4; ++sn) s_acc[sm][sn] = f32x4{0.f, 0.f, 0.f, 0.f};
  __syncthreads();

  const ushort_t* qbase = q16 + (size_t)(b * N_) * 1024 + h * 256;
  const ushort_t* kbase = kT + (size_t)bh * NC_ * 16384;
  const ushort_t* vbase = vT + (size_t)bh * 512 * 2048 + (size_t)e0 * 2048;
  const ushort_t* abase = ab + (size_t)bh * NC_ * 4096;
  ushort_t*       obase = o + (size_t)(b * N_) * 2048 + h * 512 + e0;

  bf16x8 aqP[8], bvP[2][4], aaP[2];
  LOAD_AQ(c0, aqP);
  LOAD_BV(c0, bvP);
  LOAD_AA(c0, aaP);

  for (int c = c0; c < c0 + CSEG_; ++c) {
    const float egt = egts[c];

    // consume prefetched operands (SSA copies)
    bf16x8 aq[8], bv[2][4], aa[2];
#pragma unroll
    for (int kk = 0; kk < 8; ++kk) aq[kk] = aqP[kk];
#pragma unroll
    for (int kt = 0; kt < 2; ++kt) {
      aa[kt] = aaP[kt];
#pragma unroll
      for (int n = 0; n < 4; ++n) bv[kt][n] = bvP[kt][n];
    }

    // ---- o = A@v + q@Sb   (wave w: o rows w*16..+16, cols e0..e0+64)
#pragma unroll
    for (int n = 0; n < 4; ++n) {
      f32x4 oa = f32x4{0.f, 0.f, 0.f, 0.f};
#pragma unroll
      for (int kt = 0; kt < 2; ++kt) oa = mfma16(aa[kt], bv[kt][n], oa);
#pragma unroll
      for (int kk = 0; kk < 8; ++kk) {
        bf16x8 bs = *(const bf16x8*)(&sbt[n * 16 + frow][kk * 32 + fgrp * 8]);
        oa = mfma16(aq[kk], bs, oa);
      }
#pragma unroll
      for (int j = 0; j < 4; ++j)
        obase[(size_t)(c * C_ + w * 16 + fgrp * 4 + j) * 2048 + n * 16 + frow] = f2bf(oa[j]);
    }

    // ---- S = e^gt * S + kT @ v   (wave w: d rows w*64..+64, all 64 e)
#pragma unroll
    for (int sm = 0; sm < 4; ++sm)
#pragma unroll
      for (int sn = 0; sn < 4; ++sn)
#pragma unroll
        for (int j = 0; j < 4; ++j) s_acc[sm][sn][j] *= egt;
#pragma unroll
    for (int kt = 0; kt < 2; ++kt)
#pragma unroll
      for (int sm = 0; sm < 4; ++sm) {
        bf16x8 ak = *(const bf16x8*)(kbase + (size_t)c * 16384 +
                                     (size_t)(w * 64 + sm * 16 + frow) * 64 + kt * 32 + fgrp * 8);
#pragma unroll
        for (int sn = 0; sn < 4; ++sn)
          s_acc[sm][sn] = mfma16(ak, bv[kt][sn], s_acc[sm][sn]);
      }

    // ---- prefetch next chunk's operands (issued before barriers; used after)
    if (c + 1 < c0 + CSEG_) {
      LOAD_AQ(c + 1, aqP);
      LOAD_BV(c + 1, bvP);
      LOAD_AA(c + 1, aaP);
    }

    __syncthreads();   // all waves' sbt reads of this chunk complete

    // ---- publish S^T bf16 into the (single) buffer
#pragma unroll
    for (int sm = 0; sm < 4; ++sm)
#pragma unroll
      for (int sn = 0; sn < 4; ++sn) {
        ushort4 pk;
        pk.x = f2bf(s_acc[sm][sn][0]); pk.y = f2bf(s_acc[sm][sn][1]);
        pk.z = f2bf(s_acc[sm][sn][2]); pk.w = f2bf(s_acc[sm][sn][3]);
        *(ushort4*)&sbt[sn * 16 + frow][w * 64 + sm * 16 + fgrp * 4] = pk;
      }
    __syncthreads();   // publish visible; next chunk reads sbt
  }

  // ---- write segment-final state U (fp32) for segments 0..2
  if (sg < NSEG_ - 1) {
    float* ub = U + (size_t)(bh * (NSEG_ - 1) + sg) * 256 * 512;
#pragma unroll
    for (int sm = 0; sm < 4; ++sm)
#pragma unroll
      for (int sn = 0; sn < 4; ++sn)
#pragma unroll
        for (int j = 0; j < 4; ++j)
          ub[(size_t)(w * 64 + sm * 16 + fgrp * 4 + j) * 512 + e0 + sn * 16 + frow] =
              s_acc[sm][sn][j];
  }
}

// ---------------------------------------------------------------------------
// Cross-segment correction with inlined combine (fp32 recurrence from U).
// o[t] += D_c * (q16[t] @ S_in(seg)).  grid (16 bh, 32 vb, 3), seg = z+1.
// ---------------------------------------------------------------------------
__global__ __launch_bounds__(256) void correct_kernel(
    const ushort_t* __restrict__ q16, const float* __restrict__ U,
    const float* __restrict__ gc, ushort_t* __restrict__ o) {
  const int bh = blockIdx.x, vb = blockIdx.y, z = blockIdx.z;
  const int sg = z + 1, c0 = sg * CSEG_;
  const int b = bh >> 2, h = bh & 3;
  __shared__ ushort_t sT[16][264];
  __shared__ float dseg[CSEG_];
  const int tid = threadIdx.x;
  const int w = tid >> 6, l = tid & 63;
  const int frow = l & 15, fgrp = l >> 4;

  {  // inlined combine: thread covers e = tid>>4, d = (tid&15)*16 .. +16
    const int e = tid >> 4, dbase = (tid & 15) * 16;
    float E[NSEG_ - 1];
#pragma unroll
    for (int s = 0; s < NSEG_ - 1; ++s) {
      float gsum = 0.f;
      for (int c = s * CSEG_; c < (s + 1) * CSEG_; ++c)
        gsum += gc[(size_t)bh * N_ + c * C_ + 63];
      E[s] = expf(gsum);
    }
#pragma unroll
    for (int d = 0; d < 16; ++d) {
      float S = 0.f;
      for (int s = 0; s <= z; ++s)
        S = E[s] * S + U[(size_t)(bh * (NSEG_ - 1) + s) * 256 * 512 +
                         (size_t)(dbase + d) * 512 + vb * 16 + e];
      sT[e][dbase + d] = f2bf(S);
    }
  }
  if (tid < CSEG_) {
    float s = 0.f;
    for (int i = 0; i < tid; ++i) s += gc[(size_t)bh * N_ + (c0 + i) * C_ + 63];
    dseg[tid] = expf(s);
  }
  __syncthreads();

  const ushort_t* qbase = q16 + (size_t)(b * N_) * 1024 + h * 256;
  ushort_t* obase = o + (size_t)(b * N_) * 2048 + h * 512 + vb * 16;

  for (int c = c0; c < c0 + CSEG_; ++c) {
    const float D = dseg[c - c0];
    f32x4 oa = f32x4{0.f, 0.f, 0.f, 0.f};
#pragma unroll
    for (int kk = 0; kk < 8; ++kk) {
      bf16x8 aq = *(const bf16x8*)(qbase + (size_t)(c * C_ + w * 16 + frow) * 1024 + kk * 32 + fgrp * 8);
      bf16x8 bs = *(const bf16x8*)(&sT[frow][kk * 32 + fgrp * 8]);
      oa = mfma16(aq, bs, oa);
    }
#pragma unroll
    for (int j = 0; j < 4; ++j) {
      const size_t idx = (size_t)(c * C_ + w * 16 + fgrp * 4 + j) * 2048 + frow;
      obase[idx] = f2bf(bf2f(obase[idx]) + D * oa[j]);
    }
  }
}

// ---------------------------------------------------------------------------
// ob(bf16) <- RMSNorm(o bf16)*gnorm_w * swish(g), g from fused qkvg16
// ---------------------------------------------------------------------------
__global__ __launch_bounds__(256) void normgate_kernel(const ushort_t* __restrict__ o,
    const ushort_t* __restrict__ qkvg16, const float* __restrict__ w,
    ushort_t* __restrict__ ob) {
  const int blk = blockIdx.x;          // row*NH + h
  const int row = blk >> 2, h = blk & 3;
  const size_t base = (size_t)blk * DV_;
  const size_t gbase = (size_t)row * QW_ + 4096 + h * DV_;
  const int tid = threadIdx.x;
  __shared__ float red2[256];
  const float v0 = bf2f(o[base + tid]), v1 = bf2f(o[base + tid + 256]);
  red2[tid] = v0 * v0 + v1 * v1;
  __syncthreads();
  for (int off = 128; off; off >>= 1) {
    if (tid < off) red2[tid] += red2[tid + off];
    __syncthreads();
  }
  const float rms = rsqrtf(red2[0] * (1.0f / 512.0f) + 1e-5f);
  const float g0 = bf2f(qkvg16[gbase + tid]), g1 = bf2f(qkvg16[gbase + tid + 256]);
  const float sw0 = g0 / (1.f + expf(-g0));
  const float sw1 = g1 / (1.f + expf(-g1));
  ob[base + tid]       = f2bf(v0 * rms * w[tid] * sw0);
  ob[base + tid + 256] = f2bf(v1 * rms * w[tid + 256] * sw1);
}

// ---------------------------------------------------------------------------
// Workspace (float units), total 59,834,368 fl = 228.25 MiB (R7-proven size):
//   gk 32K | gc 32K | qkvg16 25.17M | o 8.39M | ab16 1.05M |
//   q16 4.19M | kTp 4.19M | vTp 8.39M | xb 4.19M | W*T 4.19M
// Aliases (time-disjoint, verified against launch order):
//   U  (6.29M fp32) = xb+WqT+WkT+WvT  [all dead after fused qkvg GEMM;
//                                      WoT (beyond) untouched]
//   ob (8.39M fl)   = vTp             [dead after scan]
// ---------------------------------------------------------------------------
extern "C" void kernel_launch(void* const* d_in, const int* in_sizes, int n_in,
                              void* d_out, int out_size, void* d_ws, size_t ws_size,
                              hipStream_t stream) {
  (void)in_sizes; (void)n_in; (void)out_size; (void)ws_size;
  const float* x    = (const float*)d_in[0];
  const float* Wq   = (const float*)d_in[1];
  const float* Wk   = (const float*)d_in[2];
  const float* Wv   = (const float*)d_in[3];
  const float* Wg   = (const float*)d_in[4];
  const float* Wgk  = (const float*)d_in[5];
  const float* bgk  = (const float*)d_in[6];
  const float* Wo   = (const float*)d_in[7];
  const float* gw   = (const float*)d_in[8];

  float* ws = (float*)d_ws;
  size_t off = 0;
  float* gk = ws + off; off += (size_t)16 * N_;
  float* gc = ws + off; off += (size_t)16 * N_;
  ushort_t* qkvg16 = (ushort_t*)(ws + off); off += (size_t)M_ * QW_ / 2;
  ushort_t* o    = (ushort_t*)(ws + off); off += (size_t)M_ * 2048 / 2;
  ushort_t* ab16 = (ushort_t*)(ws + off); off += (size_t)16 * NC_ * 4096 / 2;
  ushort_t* q16  = (ushort_t*)(ws + off); off += (size_t)M_ * 1024 / 2;
  ushort_t* kTp  = (ushort_t*)(ws + off); off += (size_t)16 * NC_ * 16384 / 2;
  ushort_t* vTp  = (ushort_t*)(ws + off); size_t vTp_off = off; off += (size_t)16 * 512 * 2048 / 2;
  ushort_t* xb   = (ushort_t*)(ws + off); size_t xb_off = off; off += (size_t)M_ * HID_ / 2;
  ushort_t* WqT  = (ushort_t*)(ws + off); off += (size_t)1024 * 1024 / 2;
  ushort_t* WkT  = (ushort_t*)(ws + off); off += (size_t)1024 * 1024 / 2;
  ushort_t* WvT  = (ushort_t*)(ws + off); off += (size_t)2048 * 1024 / 2;
  ushort_t* WgT  = (ushort_t*)(ws + off); off += (size_t)2048 * 1024 / 2;
  ushort_t* WoT  = (ushort_t*)(ws + off); off += (size_t)1024 * 2048 / 2;
  // time-disjoint aliases (see table above)
  float*    U    = ws + xb_off;                            // 6.29M fl over xb+W[qkv]T
  ushort_t* ob   = (ushort_t*)(ws + vTp_off);              // 8.39M fl over vTp

  dim3 thr(256);
  prep_all<<<16384, thr, 0, stream>>>(Wq, Wk, Wv, Wg, Wo, x, Wgk, bgk,
                                      WqT, WkT, WvT, WgT, WoT, xb, gk);

  // fused q|k|v|g projection: BT = [WqT;WkT;WvT;WgT] (contiguous), bf16 out
  gemm_mfma<true><<<dim3(48, 32), 512, 0, stream>>>(xb, WqT, qkvg16, QW_, 1024);
  post_qkv<<<6144, thr, 0, stream>>>(qkvg16, gk, gc, ab16, kTp, vTp, q16);
  scan_mfma<<<dim3(16, 8, NSEG_), thr, 0, stream>>>(q16, kTp, vTp, ab16, gc, o, U);
  correct_kernel<<<dim3(16, 32, NSEG_ - 1), thr, 0, stream>>>(q16, U, gc, o);
  normgate_kernel<<<M_ * NH_, thr, 0, stream>>>(o, qkvg16, gw, ob);
  gemm_mfma<false><<<dim3(8, 32), 512, 0, stream>>>(ob, WoT, (float*)d_out, 1024, 2048);
}

// Round 27
// 388.346 us; speedup vs baseline: 1.0288x; 1.0288x over previous
//
#include <hip/hip_runtime.h>

// Problem constants (fixed by the reference)
constexpr int B_  = 4;
constexpr int N_  = 2048;
constexpr int HID_ = 1024;
constexpr int NH_ = 4;
constexpr int DK_ = 256;
constexpr int DV_ = 512;
constexpr int C_  = 64;     // chunk size
constexpr int NC_ = 32;     // chunks per sequence
constexpr int M_  = B_ * N_;  // 8192 rows
constexpr int NSEG_ = 4;    // scan segments
constexpr int CSEG_ = NC_ / NSEG_;  // 8 chunks per segment
constexpr int QW_ = 6144;   // fused q|k|v|g row width

using ushort_t = unsigned short;
typedef __attribute__((ext_vector_type(8))) short bf16x8;
typedef __attribute__((ext_vector_type(4))) float f32x4;

__device__ __forceinline__ ushort_t f2bf(float f) {
  union { float fv; unsigned u; } v; v.fv = f;
  unsigned r = v.u + 0x7FFFu + ((v.u >> 16) & 1u);   // round-to-nearest-even
  return (ushort_t)(r >> 16);
}
__device__ __forceinline__ float bf2f(ushort_t u) {
  union { unsigned u; float f; } v; v.u = ((unsigned)u) << 16; return v.f;
}

__device__ __forceinline__ void gload_lds16(const void* g, void* l) {
  __builtin_amdgcn_global_load_lds(
      (const __attribute__((address_space(1))) unsigned int*)g,
      (__attribute__((address_space(3))) unsigned int*)l, 16, 0, 0);
}

__device__ __forceinline__ f32x4 mfma16(bf16x8 a, bf16x8 b, f32x4 c) {
  return __builtin_amdgcn_mfma_f32_16x16x32_bf16(a, b, c, 0, 0, 0);
}

// ---------------------------------------------------------------------------
// bf16 MFMA GEMM, TRIPLE-buffered BK=32 counted-vmcnt pipeline (R23-proven)
// + R27: bijective XCD swizzle (nwg%8==0 for both call sites) and
//   s_setprio(1) around the MFMA cluster (T5).  Both are pure scheduling
//   changes on independent blocks -> bit-identical output.
// 256x128 tile, 512 thr = 8 waves.  LDS 72 KB -> 2 blocks/CU.
// ---------------------------------------------------------------------------
#define GSTAGE_A(G, Kd, kt32, dst)                                             \
  do {                                                                         \
    _Pragma("unroll")                                                          \
    for (int j = 0; j < 2; ++j) {                                              \
      const int cb = j * 8 + wave;                /* 0..15 */                  \
      const int srow = (cb * 64 + lane) >> 2;     /* 0..255 */                 \
      gload_lds16((G) + (size_t)srow * (Kd) + (kt32) * 32 + kp,                \
                  (dst) + cb * 512);                                           \
    }                                                                          \
  } while (0)
#define GSTAGE_B(G, Kd, kt32, dst)                                             \
  do {                                                                         \
    const int cb = wave;                          /* 0..7 */                   \
    const int srow = (cb * 64 + lane) >> 2;       /* 0..127 */                 \
    gload_lds16((G) + (size_t)srow * (Kd) + (kt32) * 32 + kp,                  \
                (dst) + cb * 512);                                             \
  } while (0)

template<bool BF16OUT>
__global__ __launch_bounds__(512) void gemm_mfma(
    const ushort_t* __restrict__ A, const ushort_t* __restrict__ BT,
    void* __restrict__ CV, int N, int K) {
  __shared__ ushort_t Ah[3][256 * 32];   // 48 KB
  __shared__ ushort_t Bh[3][128 * 32];   // 24 KB
  const int tid = threadIdx.x;
  const int wave = tid >> 6, lane = tid & 63;
  // ---- XCD-aware bijective block swizzle (nwg % 8 == 0 at both call sites)
  const int nwg = (int)(gridDim.x * gridDim.y);
  int fid = (int)(blockIdx.y * gridDim.x + blockIdx.x);
  const int cpx = nwg >> 3;
  fid = (fid & 7) * cpx + (fid >> 3);
  const int bx = fid % (int)gridDim.x;
  const int by = fid / (int)gridDim.x;
  const size_t brow = (size_t)by * 256;
  const size_t bcol = (size_t)bx * 128;
  const int wr = (wave >> 1) * 64, wc = (wave & 1) * 64;
  const int frow = lane & 15;
  const int fko  = ((lane >> 4) ^ (frow & 3)) * 8;          // swizzled read k-off
  const int kp   = (((lane & 3) ^ ((lane >> 2) & 3)) * 8);  // inverse-swz src k-off

  f32x4 acc[4][4];
#pragma unroll
  for (int m = 0; m < 4; ++m)
#pragma unroll
    for (int n = 0; n < 4; ++n) acc[m][n] = f32x4{0.f, 0.f, 0.f, 0.f};

  const ushort_t* Ag = A + brow * K;
  const ushort_t* Bg = BT + bcol * K;
  const int NT = K >> 5;                 // K-tiles of 32

  GSTAGE_A(Ag, K, 0, Ah[0]);
  GSTAGE_B(Bg, K, 0, Bh[0]);
  GSTAGE_A(Ag, K, 1, Ah[1]);
  GSTAGE_B(Bg, K, 1, Bh[1]);
  asm volatile("s_waitcnt vmcnt(3)" ::: "memory");
  __builtin_amdgcn_s_barrier();

  int rb = 0, sb = 2;                    // read buf, stage buf
  bf16x8 af[4], bfr[4];
  for (int kt = 0; kt < NT; ++kt) {
#pragma unroll
    for (int m = 0; m < 4; ++m)
      af[m] = *(const bf16x8*)(&Ah[rb][(wr + m * 16 + frow) * 32 + fko]);
#pragma unroll
    for (int n = 0; n < 4; ++n)
      bfr[n] = *(const bf16x8*)(&Bh[rb][(wc + n * 16 + frow) * 32 + fko]);
    if (kt + 2 < NT) {
      GSTAGE_A(Ag, K, kt + 2, Ah[sb]);
      GSTAGE_B(Bg, K, kt + 2, Bh[sb]);
    }
    __builtin_amdgcn_s_setprio(1);
#pragma unroll
    for (int m = 0; m < 4; ++m)
#pragma unroll
      for (int n = 0; n < 4; ++n) acc[m][n] = mfma16(af[m], bfr[n], acc[m][n]);
    __builtin_amdgcn_s_setprio(0);
    if (kt + 1 < NT) {
      if (kt + 2 < NT) asm volatile("s_waitcnt vmcnt(3)" ::: "memory");
      else             asm volatile("s_waitcnt vmcnt(0)" ::: "memory");
      __builtin_amdgcn_s_barrier();
    }
    rb = (rb == 2) ? 0 : rb + 1;
    sb = (sb == 2) ? 0 : sb + 1;
  }

  const int crow = (lane >> 4) * 4;
  const int ccol = lane & 15;
#pragma unroll
  for (int m = 0; m < 4; ++m)
#pragma unroll
    for (int n = 0; n < 4; ++n) {
      const size_t base = (brow + wr + m * 16 + crow) * (size_t)N + (bcol + wc + n * 16 + ccol);
      if constexpr (BF16OUT) {
        ushort_t* Out = (ushort_t*)CV;
#pragma unroll
        for (int j = 0; j < 4; ++j) Out[base + (size_t)j * N] = f2bf(acc[m][n][j]);
      } else {
        float* Out = (float*)CV;
#pragma unroll
        for (int j = 0; j < 4; ++j) Out[base + (size_t)j * N] = acc[m][n][j];
      }
    }
}

// ---------------------------------------------------------------------------
// Fused prologue: 5 weight transposes + {x->bf16 AND gk} per row.
// ---------------------------------------------------------------------------
__global__ __launch_bounds__(256) void prep_all(
    const float* __restrict__ Wq, const float* __restrict__ Wk,
    const float* __restrict__ Wv, const float* __restrict__ Wg,
    const float* __restrict__ Wo, const float* __restrict__ x,
    const float* __restrict__ Wgk, const float* __restrict__ bgk,
    ushort_t* __restrict__ WqT, ushort_t* __restrict__ WkT,
    ushort_t* __restrict__ WvT, ushort_t* __restrict__ WgT,
    ushort_t* __restrict__ WoT, ushort_t* __restrict__ xb,
    float* __restrict__ gkbuf) {
  __shared__ float tile[32][33];
  __shared__ float4 red4[256];
  const int blk = blockIdx.x;
  const int tid = threadIdx.x;
  if (blk >= 8192) {   // x -> bf16 + gk: one row (1024 floats) per block
    const int row = blk - 8192;
    const size_t i = ((size_t)row * 1024) + tid * 4;
    float4 v = *(const float4*)(x + i);
    ushort4 r;
    r.x = f2bf(v.x); r.y = f2bf(v.y); r.z = f2bf(v.z); r.w = f2bf(v.w);
    *(ushort4*)(xb + i) = r;
    float4 p = {0.f, 0.f, 0.f, 0.f};
    const float4* wg4 = (const float4*)Wgk;   // [1024] rows of 4
    const float xv[4] = {v.x, v.y, v.z, v.w};
#pragma unroll
    for (int j = 0; j < 4; ++j) {
      float4 wg = wg4[tid * 4 + j];
      p.x += xv[j] * wg.x; p.y += xv[j] * wg.y;
      p.z += xv[j] * wg.z; p.w += xv[j] * wg.w;
    }
    red4[tid] = p;
    __syncthreads();
    for (int off2 = 128; off2; off2 >>= 1) {
      if (tid < off2) {
        float4 a = red4[tid], b4 = red4[tid + off2];
        a.x += b4.x; a.y += b4.y; a.z += b4.z; a.w += b4.w;
        red4[tid] = a;
      }
      __syncthreads();
    }
    if (tid < 4) {
      const float z  = (&red4[0].x)[tid] + bgk[tid];
      const float ls = fminf(z, 0.f) - log1pf(expf(-fabsf(z)));
      const int b = row >> 11, n = row & 2047;
      gkbuf[((size_t)(b * NH_ + tid)) * N_ + n] = ls * (1.0f / 16.0f);
    }
    return;
  }
  const float* W; ushort_t* WT; int K, Nn, gxw, local;
  if (blk < 1024)      { W = Wq; WT = WqT; K = 1024; Nn = 1024; gxw = 32; local = blk; }
  else if (blk < 2048) { W = Wk; WT = WkT; K = 1024; Nn = 1024; gxw = 32; local = blk - 1024; }
  else if (blk < 4096) { W = Wv; WT = WvT; K = 1024; Nn = 2048; gxw = 64; local = blk - 2048; }
  else if (blk < 6144) { W = Wg; WT = WgT; K = 1024; Nn = 2048; gxw = 64; local = blk - 4096; }
  else                 { W = Wo; WT = WoT; K = 2048; Nn = 1024; gxw = 32; local = blk - 6144; }
  const int n0 = (local % gxw) * 32, k0 = (local / gxw) * 32;
  const int tx = tid & 31, ty = tid >> 5;
#pragma unroll
  for (int i = 0; i < 32; i += 8)
    tile[ty + i][tx] = W[(size_t)(k0 + ty + i) * Nn + n0 + tx];
  __syncthreads();
#pragma unroll
  for (int i = 0; i < 32; i += 8)
    WT[(size_t)(n0 + ty + i) * K + k0 + tx] = f2bf(tile[tx][ty + i]);
}

// ---------------------------------------------------------------------------
// per-(bh,chunk) inclusive cumsum of gk
// ---------------------------------------------------------------------------
__global__ __launch_bounds__(64) void cumsum_kernel(const float* __restrict__ gkbuf,
                                                    float* __restrict__ gcbuf) {
  const int bh = blockIdx.x;
  const int c  = threadIdx.x;
  if (c < NC_) {
    const size_t base = (size_t)bh * N_ + c * C_;
    float acc = 0.f;
    for (int t = 0; t < C_; ++t) { acc += gkbuf[base + t]; gcbuf[base + t] = acc; }
  }
}

// ---------------------------------------------------------------------------
// Fused post-qkv stage (reads fused qkvg16 [8192][6144]):
//   [0,512) a_mfma | [512,1024) pack_kT | [1024,2048) pack_vT |
//   [2048,6144) pack_q16
// ---------------------------------------------------------------------------
__global__ __launch_bounds__(256) void post_qkv(
    const ushort_t* __restrict__ qkvg16, const float* __restrict__ gc,
    ushort_t* __restrict__ Abuf, ushort_t* __restrict__ kT,
    ushort_t* __restrict__ vT, ushort_t* __restrict__ q16) {
  __shared__ __align__(16) char smem[256 * 68 * 2 + 256];
  const int gblk = blockIdx.x;
  const int tid = threadIdx.x;

  if (gblk < 512) {               // ---------------- a_mfma
    const int blk = gblk;
    const int bh  = blk >> 5, c = blk & 31;
    const int b   = bh >> 2, h = bh & 3;
    float* gcs = (float*)smem;    // [64]
    const int w = tid >> 6, l = tid & 63;
    const int frow = l & 15, fgrp = l >> 4;
    if (tid < 64) gcs[tid] = gc[(size_t)bh * N_ + c * C_ + tid];
    __syncthreads();

    const size_t rbase = (size_t)(b * N_ + c * C_);
    bf16x8 aqr[8];
#pragma unroll
    for (int kk = 0; kk < 8; ++kk)
      aqr[kk] = *(const bf16x8*)(qkvg16 + (rbase + w * 16 + frow) * QW_ +
                                 h * 256 + kk * 32 + fgrp * 8);

    ushort_t* ab = Abuf + (size_t)blk * 4096;
    const float scl = 0.0625f;
#pragma unroll
    for (int n = 0; n < 4; ++n) {
      f32x4 acc = f32x4{0.f, 0.f, 0.f, 0.f};
#pragma unroll
      for (int kk = 0; kk < 8; ++kk) {
        bf16x8 bk = *(const bf16x8*)(qkvg16 + (rbase + n * 16 + frow) * QW_ +
                                     1024 + h * 256 + kk * 32 + fgrp * 8);
        acc = mfma16(aqr[kk], bk, acc);
      }
      const int s = n * 16 + frow;
      const float gcss = gcs[s];
#pragma unroll
      for (int j = 0; j < 4; ++j) {
        const int t = w * 16 + fgrp * 4 + j;
        const float val = (s <= t) ? acc[j] * scl * expf(gcs[t] - gcss) : 0.f;
        ab[(size_t)t * 64 + s] = f2bf(val);
      }
    }
  } else if (gblk < 1024) {       // ---------------- pack_kT
    const int blk = gblk - 512;
    const int bh = blk >> 5, c = blk & 31;
    const int b = bh >> 2, h = bh & 3;
    ushort_t (*kl)[68] = (ushort_t (*)[68])smem;           // [256][68]
    float* fk = (float*)(smem + 256 * 68 * 2);             // [64]
    if (tid < 64) {
      const float gct = gc[(size_t)bh * N_ + c * C_ + tid];
      const float gt  = gc[(size_t)bh * N_ + c * C_ + 63];
      fk[tid] = expf(gt - gct);
    }
    __syncthreads();
    const ushort_t* kb = qkvg16 + (size_t)(b * N_ + c * C_) * QW_ + 1024 + h * 256;
    for (int it = 0; it < 8; ++it) {
      const int e = it * 256 + tid;
      const int t = e >> 5, d8 = (e & 31) * 8;
      bf16x8 kv = *(const bf16x8*)(kb + (size_t)t * QW_ + d8);
      const float f = fk[t];
#pragma unroll
      for (int j = 0; j < 8; ++j) kl[d8 + j][t] = f2bf(bf2f((ushort_t)kv[j]) * f);
    }
    __syncthreads();
    ushort_t* out = kT + (size_t)blk * 16384;
    for (int it = 0; it < 8; ++it) {
      const int e = it * 256 + tid;
      const int d = e >> 3, t8 = (e & 7) * 8;
      ushort4 lo, hi;
      lo.x = kl[d][t8 + 0]; lo.y = kl[d][t8 + 1]; lo.z = kl[d][t8 + 2]; lo.w = kl[d][t8 + 3];
      hi.x = kl[d][t8 + 4]; hi.y = kl[d][t8 + 5]; hi.z = kl[d][t8 + 6]; hi.w = kl[d][t8 + 7];
      *(ushort4*)(out + (size_t)d * 64 + t8)     = lo;
      *(ushort4*)(out + (size_t)d * 64 + t8 + 4) = hi;
    }
  } else if (gblk < 2048) {       // ---------------- pack_vT
    const int blk = gblk - 1024;
    const int eh = blk & 1, c = (blk >> 1) & 31, bh = blk >> 6;
    const int b = bh >> 2, h = bh & 3;
    ushort_t (*vl)[68] = (ushort_t (*)[68])smem;           // [256][68]
    const ushort_t* vb = qkvg16 + (size_t)(b * N_ + c * C_) * QW_ + 2048 + h * 512 + eh * 256;
    for (int it = 0; it < 8; ++it) {
      const int e = it * 256 + tid;
      const int s = e >> 5, c8 = (e & 31) * 8;
      bf16x8 val = *(const bf16x8*)(vb + (size_t)s * QW_ + c8);
#pragma unroll
      for (int j = 0; j < 8; ++j) vl[c8 + j][s] = (ushort_t)val[j];
    }
    __syncthreads();
    ushort_t* out = vT + (size_t)bh * 512 * 2048 + (size_t)(eh * 256) * 2048 + c * C_;
    for (int it = 0; it < 8; ++it) {
      const int e = it * 256 + tid;
      const int r = e >> 3, t8 = (e & 7) * 8;
      ushort4 lo, hi;
      lo.x = vl[r][t8 + 0]; lo.y = vl[r][t8 + 1]; lo.z = vl[r][t8 + 2]; lo.w = vl[r][t8 + 3];
      hi.x = vl[r][t8 + 4]; hi.y = vl[r][t8 + 5]; hi.z = vl[r][t8 + 6]; hi.w = vl[r][t8 + 7];
      *(ushort4*)(out + (size_t)r * 2048 + t8)     = lo;
      *(ushort4*)(out + (size_t)r * 2048 + t8 + 4) = hi;
    }
  } else {                        // ---------------- pack_q16
    const size_t i8 = ((size_t)(gblk - 2048) * 256 + tid) * 8;   // < M*1024
    const int row = (int)(i8 >> 10);
    const int col = (int)(i8 & 1023);
    const int b = row >> 11, n = row & 2047;
    const int h = col >> 8;
    const float f = 0.0625f * expf(gc[(size_t)(b * NH_ + h) * N_ + n]);
    bf16x8 v = *(const bf16x8*)(qkvg16 + (size_t)row * QW_ + col);
    ushort_t r[8];
#pragma unroll
    for (int j = 0; j < 8; ++j) r[j] = f2bf(bf2f((ushort_t)v[j]) * f);
    *(bf16x8*)(q16 + i8) = *(bf16x8*)r;
  }
}

// ---------------------------------------------------------------------------
// Segmented MFMA chunk scan, EBLK=64, cross-barrier prefetch of aq+bv+aa.
// SINGLE S^T buffer (33.8 KB LDS -> 4 WG/CU) with 2 barriers/chunk.
// grid = (16 bh, 8 vblk, 4 seg), wgid%8 = bh%8 (XCD affinity).
// ---------------------------------------------------------------------------
#define LOAD_AQ(cc, dst)                                                       \
  do {                                                                         \
    _Pragma("unroll")                                                          \
    for (int kk = 0; kk < 8; ++kk)                                             \
      dst[kk] = *(const bf16x8*)(qbase + (size_t)((cc) * C_ + w * 16 + frow) * 1024 + \
                                 kk * 32 + fgrp * 8);                          \
  } while (0)
#define LOAD_BV(cc, dst)                                                       \
  do {                                                                         \
    _Pragma("unroll")                                                          \
    for (int kt = 0; kt < 2; ++kt)                                             \
      _Pragma("unroll")                                                        \
      for (int n = 0; n < 4; ++n)                                              \
        dst[kt][n] = *(const bf16x8*)(vbase + (size_t)(n * 16 + frow) * 2048 + \
                                      (cc) * C_ + kt * 32 + fgrp * 8);         \
  } while (0)
#define LOAD_AA(cc, dst)                                                       \
  do {                                                                         \
    _Pragma("unroll")                                                          \
    for (int kt = 0; kt < 2; ++kt)                                             \
      dst[kt] = *(const bf16x8*)(abase + (size_t)(cc) * 4096 +                 \
                                 (w * 16 + frow) * 64 + kt * 32 + fgrp * 8);   \
  } while (0)

__global__ __launch_bounds__(256) void scan_mfma(
    const ushort_t* __restrict__ q16,   // [8192][1024] pre-scaled bf16
    const ushort_t* __restrict__ kT,    // [bh][c][256][64] decayed bf16
    const ushort_t* __restrict__ vT,    // [bh][512][2048] bf16
    const ushort_t* __restrict__ ab,    // [bh*32+c][64][64] bf16
    const float*    __restrict__ gc,
    ushort_t* __restrict__ o,           // [8192][2048] bf16 (intra-segment part)
    float*    __restrict__ U) {         // [bh][seg 0..2][256][512] fp32
  const int bh = blockIdx.x, vblk = blockIdx.y, sg = blockIdx.z;
  const int b = bh >> 2, h = bh & 3;
  const int e0 = vblk * 64;
  const int c0 = sg * CSEG_;
  __shared__ ushort_t sbt[64][264];     // S^T bf16 single buffer (33.8 KB)
  __shared__ float egts[NC_];
  const int tid = threadIdx.x;
  const int w = tid >> 6, l = tid & 63;
  const int frow = l & 15, fgrp = l >> 4;

  for (int i = tid; i < 64 * 264 / 2; i += 256) ((unsigned*)&sbt[0][0])[i] = 0u;
  if (tid < NC_) egts[tid] = expf(gc[(size_t)bh * N_ + tid * C_ + 63]);
  f32x4 s_acc[4][4];
#pragma unroll
  for (int sm = 0; sm < 4; ++sm)
#pragma unroll
    for (int sn = 0; sn < 4; ++sn) s_acc[sm][sn] = f32x4{0.f, 0.f, 0.f, 0.f};
  __syncthreads();

  const ushort_t* qbase = q16 + (size_t)(b * N_) * 1024 + h * 256;
  const ushort_t* kbase = kT + (size_t)bh * NC_ * 16384;
  const ushort_t* vbase = vT + (size_t)bh * 512 * 2048 + (size_t)e0 * 2048;
  const ushort_t* abase = ab + (size_t)bh * NC_ * 4096;
  ushort_t*       obase = o + (size_t)(b * N_) * 2048 + h * 512 + e0;

  bf16x8 aqP[8], bvP[2][4], aaP[2];
  LOAD_AQ(c0, aqP);
  LOAD_BV(c0, bvP);
  LOAD_AA(c0, aaP);

  for (int c = c0; c < c0 + CSEG_; ++c) {
    const float egt = egts[c];

    // consume prefetched operands (SSA copies)
    bf16x8 aq[8], bv[2][4], aa[2];
#pragma unroll
    for (int kk = 0; kk < 8; ++kk) aq[kk] = aqP[kk];
#pragma unroll
    for (int kt = 0; kt < 2; ++kt) {
      aa[kt] = aaP[kt];
#pragma unroll
      for (int n = 0; n < 4; ++n) bv[kt][n] = bvP[kt][n];
    }

    // ---- o = A@v + q@Sb   (wave w: o rows w*16..+16, cols e0..e0+64)
#pragma unroll
    for (int n = 0; n < 4; ++n) {
      f32x4 oa = f32x4{0.f, 0.f, 0.f, 0.f};
#pragma unroll
      for (int kt = 0; kt < 2; ++kt) oa = mfma16(aa[kt], bv[kt][n], oa);
#pragma unroll
      for (int kk = 0; kk < 8; ++kk) {
        bf16x8 bs = *(const bf16x8*)(&sbt[n * 16 + frow][kk * 32 + fgrp * 8]);
        oa = mfma16(aq[kk], bs, oa);
      }
#pragma unroll
      for (int j = 0; j < 4; ++j)
        obase[(size_t)(c * C_ + w * 16 + fgrp * 4 + j) * 2048 + n * 16 + frow] = f2bf(oa[j]);
    }

    // ---- S = e^gt * S + kT @ v   (wave w: d rows w*64..+64, all 64 e)
#pragma unroll
    for (int sm = 0; sm < 4; ++sm)
#pragma unroll
      for (int sn = 0; sn < 4; ++sn)
#pragma unroll
        for (int j = 0; j < 4; ++j) s_acc[sm][sn][j] *= egt;
#pragma unroll
    for (int kt = 0; kt < 2; ++kt)
#pragma unroll
      for (int sm = 0; sm < 4; ++sm) {
        bf16x8 ak = *(const bf16x8*)(kbase + (size_t)c * 16384 +
                                     (size_t)(w * 64 + sm * 16 + frow) * 64 + kt * 32 + fgrp * 8);
#pragma unroll
        for (int sn = 0; sn < 4; ++sn)
          s_acc[sm][sn] = mfma16(ak, bv[kt][sn], s_acc[sm][sn]);
      }

    // ---- prefetch next chunk's operands (issued before barriers; used after)
    if (c + 1 < c0 + CSEG_) {
      LOAD_AQ(c + 1, aqP);
      LOAD_BV(c + 1, bvP);
      LOAD_AA(c + 1, aaP);
    }

    __syncthreads();   // all waves' sbt reads of this chunk complete

    // ---- publish S^T bf16 into the (single) buffer
#pragma unroll
    for (int sm = 0; sm < 4; ++sm)
#pragma unroll
      for (int sn = 0; sn < 4; ++sn) {
        ushort4 pk;
        pk.x = f2bf(s_acc[sm][sn][0]); pk.y = f2bf(s_acc[sm][sn][1]);
        pk.z = f2bf(s_acc[sm][sn][2]); pk.w = f2bf(s_acc[sm][sn][3]);
        *(ushort4*)&sbt[sn * 16 + frow][w * 64 + sm * 16 + fgrp * 4] = pk;
      }
    __syncthreads();   // publish visible; next chunk reads sbt
  }

  // ---- write segment-final state U (fp32) for segments 0..2
  if (sg < NSEG_ - 1) {
    float* ub = U + (size_t)(bh * (NSEG_ - 1) + sg) * 256 * 512;
#pragma unroll
    for (int sm = 0; sm < 4; ++sm)
#pragma unroll
      for (int sn = 0; sn < 4; ++sn)
#pragma unroll
        for (int j = 0; j < 4; ++j)
          ub[(size_t)(w * 64 + sm * 16 + fgrp * 4 + j) * 512 + e0 + sn * 16 + frow] =
              s_acc[sm][sn][j];
  }
}

// ---------------------------------------------------------------------------
// Cross-segment correction with inlined combine (fp32 recurrence from U).
// o[t] += D_c * (q16[t] @ S_in(seg)).  grid (16 bh, 32 vb, 3), seg = z+1.
// ---------------------------------------------------------------------------
__global__ __launch_bounds__(256) void correct_kernel(
    const ushort_t* __restrict__ q16, const float* __restrict__ U,
    const float* __restrict__ gc, ushort_t* __restrict__ o) {
  const int bh = blockIdx.x, vb = blockIdx.y, z = blockIdx.z;
  const int sg = z + 1, c0 = sg * CSEG_;
  const int b = bh >> 2, h = bh & 3;
  __shared__ ushort_t sT[16][264];
  __shared__ float dseg[CSEG_];
  const int tid = threadIdx.x;
  const int w = tid >> 6, l = tid & 63;
  const int frow = l & 15, fgrp = l >> 4;

  {  // inlined combine: thread covers e = tid>>4, d = (tid&15)*16 .. +16
    const int e = tid >> 4, dbase = (tid & 15) * 16;
    float E[NSEG_ - 1];
#pragma unroll
    for (int s = 0; s < NSEG_ - 1; ++s) {
      float gsum = 0.f;
      for (int c = s * CSEG_; c < (s + 1) * CSEG_; ++c)
        gsum += gc[(size_t)bh * N_ + c * C_ + 63];
      E[s] = expf(gsum);
    }
#pragma unroll
    for (int d = 0; d < 16; ++d) {
      float S = 0.f;
      for (int s = 0; s <= z; ++s)
        S = E[s] * S + U[(size_t)(bh * (NSEG_ - 1) + s) * 256 * 512 +
                         (size_t)(dbase + d) * 512 + vb * 16 + e];
      sT[e][dbase + d] = f2bf(S);
    }
  }
  if (tid < CSEG_) {
    float s = 0.f;
    for (int i = 0; i < tid; ++i) s += gc[(size_t)bh * N_ + (c0 + i) * C_ + 63];
    dseg[tid] = expf(s);
  }
  __syncthreads();

  const ushort_t* qbase = q16 + (size_t)(b * N_) * 1024 + h * 256;
  ushort_t* obase = o + (size_t)(b * N_) * 2048 + h * 512 + vb * 16;

  for (int c = c0; c < c0 + CSEG_; ++c) {
    const float D = dseg[c - c0];
    f32x4 oa = f32x4{0.f, 0.f, 0.f, 0.f};
#pragma unroll
    for (int kk = 0; kk < 8; ++kk) {
      bf16x8 aq = *(const bf16x8*)(qbase + (size_t)(c * C_ + w * 16 + frow) * 1024 + kk * 32 + fgrp * 8);
      bf16x8 bs = *(const bf16x8*)(&sT[frow][kk * 32 + fgrp * 8]);
      oa = mfma16(aq, bs, oa);
    }
#pragma unroll
    for (int j = 0; j < 4; ++j) {
      const size_t idx = (size_t)(c * C_ + w * 16 + fgrp * 4 + j) * 2048 + frow;
      obase[idx] = f2bf(bf2f(obase[idx]) + D * oa[j]);
    }
  }
}

// ---------------------------------------------------------------------------
// ob(bf16) <- RMSNorm(o bf16)*gnorm_w * swish(g), g from fused qkvg16
// ---------------------------------------------------------------------------
__global__ __launch_bounds__(256) void normgate_kernel(const ushort_t* __restrict__ o,
    const ushort_t* __restrict__ qkvg16, const float* __restrict__ w,
    ushort_t* __restrict__ ob) {
  const int blk = blockIdx.x;          // row*NH + h
  const int row = blk >> 2, h = blk & 3;
  const size_t base = (size_t)blk * DV_;
  const size_t gbase = (size_t)row * QW_ + 4096 + h * DV_;
  const int tid = threadIdx.x;
  __shared__ float red2[256];
  const float v0 = bf2f(o[base + tid]), v1 = bf2f(o[base + tid + 256]);
  red2[tid] = v0 * v0 + v1 * v1;
  __syncthreads();
  for (int off = 128; off; off >>= 1) {
    if (tid < off) red2[tid] += red2[tid + off];
    __syncthreads();
  }
  const float rms = rsqrtf(red2[0] * (1.0f / 512.0f) + 1e-5f);
  const float g0 = bf2f(qkvg16[gbase + tid]), g1 = bf2f(qkvg16[gbase + tid + 256]);
  const float sw0 = g0 / (1.f + expf(-g0));
  const float sw1 = g1 / (1.f + expf(-g1));
  ob[base + tid]       = f2bf(v0 * rms * w[tid] * sw0);
  ob[base + tid + 256] = f2bf(v1 * rms * w[tid + 256] * sw1);
}

// ---------------------------------------------------------------------------
// Workspace (float units), total 59,834,368 fl = 228.25 MiB (R7-proven size):
//   gk 32K | gc 32K | qkvg16 25.17M | o 8.39M | ab16 1.05M |
//   q16 4.19M | kTp 4.19M | vTp 8.39M | xb 4.19M | W*T 4.19M
// Aliases (time-disjoint, verified against launch order):
//   U  (6.29M fp32) = xb+WqT+WkT+WvT  [all dead after fused qkvg GEMM;
//                                      WoT (beyond) untouched]
//   ob (8.39M fl)   = vTp             [dead after scan]
// ---------------------------------------------------------------------------
extern "C" void kernel_launch(void* const* d_in, const int* in_sizes, int n_in,
                              void* d_out, int out_size, void* d_ws, size_t ws_size,
                              hipStream_t stream) {
  (void)in_sizes; (void)n_in; (void)out_size; (void)ws_size;
  const float* x    = (const float*)d_in[0];
  const float* Wq   = (const float*)d_in[1];
  const float* Wk   = (const float*)d_in[2];
  const float* Wv   = (const float*)d_in[3];
  const float* Wg   = (const float*)d_in[4];
  const float* Wgk  = (const float*)d_in[5];
  const float* bgk  = (const float*)d_in[6];
  const float* Wo   = (const float*)d_in[7];
  const float* gw   = (const float*)d_in[8];

  float* ws = (float*)d_ws;
  size_t off = 0;
  float* gk = ws + off; off += (size_t)16 * N_;
  float* gc = ws + off; off += (size_t)16 * N_;
  ushort_t* qkvg16 = (ushort_t*)(ws + off); off += (size_t)M_ * QW_ / 2;
  ushort_t* o    = (ushort_t*)(ws + off); off += (size_t)M_ * 2048 / 2;
  ushort_t* ab16 = (ushort_t*)(ws + off); off += (size_t)16 * NC_ * 4096 / 2;
  ushort_t* q16  = (ushort_t*)(ws + off); off += (size_t)M_ * 1024 / 2;
  ushort_t* kTp  = (ushort_t*)(ws + off); off += (size_t)16 * NC_ * 16384 / 2;
  ushort_t* vTp  = (ushort_t*)(ws + off); size_t vTp_off = off; off += (size_t)16 * 512 * 2048 / 2;
  ushort_t* xb   = (ushort_t*)(ws + off); size_t xb_off = off; off += (size_t)M_ * HID_ / 2;
  ushort_t* WqT  = (ushort_t*)(ws + off); off += (size_t)1024 * 1024 / 2;
  ushort_t* WkT  = (ushort_t*)(ws + off); off += (size_t)1024 * 1024 / 2;
  ushort_t* WvT  = (ushort_t*)(ws + off); off += (size_t)2048 * 1024 / 2;
  ushort_t* WgT  = (ushort_t*)(ws + off); off += (size_t)2048 * 1024 / 2;
  ushort_t* WoT  = (ushort_t*)(ws + off); off += (size_t)1024 * 2048 / 2;
  // time-disjoint aliases (see table above)
  float*    U    = ws + xb_off;                            // 6.29M fl over xb+W[qkv]T
  ushort_t* ob   = (ushort_t*)(ws + vTp_off);              // 8.39M fl over vTp

  dim3 thr(256);
  prep_all<<<16384, thr, 0, stream>>>(Wq, Wk, Wv, Wg, Wo, x, Wgk, bgk,
                                      WqT, WkT, WvT, WgT, WoT, xb, gk);

  // fused q|k|v|g projection: BT = [WqT;WkT;WvT;WgT] (contiguous), bf16 out
  gemm_mfma<true><<<dim3(48, 32), 512, 0, stream>>>(xb, WqT, qkvg16, QW_, 1024);
  cumsum_kernel<<<16, 64, 0, stream>>>(gk, gc);
  post_qkv<<<6144, thr, 0, stream>>>(qkvg16, gc, ab16, kTp, vTp, q16);
  scan_mfma<<<dim3(16, 8, NSEG_), thr, 0, stream>>>(q16, kTp, vTp, ab16, gc, o, U);
  correct_kernel<<<dim3(16, 32, NSEG_ - 1), thr, 0, stream>>>(q16, U, gc, o);
  normgate_kernel<<<M_ * NH_, thr, 0, stream>>>(o, qkvg16, gw, ob);
  gemm_mfma<false><<<dim3(8, 32), 512, 0, stream>>>(ob, WoT, (float*)d_out, 1024, 2048);
}

// Round 28
// 381.630 us; speedup vs baseline: 1.0469x; 1.0176x over previous
//
#include <hip/hip_runtime.h>

// Problem constants (fixed by the reference)
constexpr int B_  = 4;
constexpr int N_  = 2048;
constexpr int HID_ = 1024;
constexpr int NH_ = 4;
constexpr int DK_ = 256;
constexpr int DV_ = 512;
constexpr int C_  = 64;     // chunk size
constexpr int NC_ = 32;     // chunks per sequence
constexpr int M_  = B_ * N_;  // 8192 rows
constexpr int NSEG_ = 4;    // scan segments
constexpr int CSEG_ = NC_ / NSEG_;  // 8 chunks per segment
constexpr int QW_ = 6144;   // fused q|k|v|g row width

using ushort_t = unsigned short;
typedef __attribute__((ext_vector_type(8))) short bf16x8;
typedef __attribute__((ext_vector_type(4))) float f32x4;

__device__ __forceinline__ ushort_t f2bf(float f) {
  union { float fv; unsigned u; } v; v.fv = f;
  unsigned r = v.u + 0x7FFFu + ((v.u >> 16) & 1u);   // round-to-nearest-even
  return (ushort_t)(r >> 16);
}
__device__ __forceinline__ float bf2f(ushort_t u) {
  union { unsigned u; float f; } v; v.u = ((unsigned)u) << 16; return v.f;
}

__device__ __forceinline__ void gload_lds16(const void* g, void* l) {
  __builtin_amdgcn_global_load_lds(
      (const __attribute__((address_space(1))) unsigned int*)g,
      (__attribute__((address_space(3))) unsigned int*)l, 16, 0, 0);
}

__device__ __forceinline__ f32x4 mfma16(bf16x8 a, bf16x8 b, f32x4 c) {
  return __builtin_amdgcn_mfma_f32_16x16x32_bf16(a, b, c, 0, 0, 0);
}

// ---------------------------------------------------------------------------
// Shared staging macros (k-slot XOR swizzle, involution on both sides).
// ---------------------------------------------------------------------------
#define GSTAGE_A(G, Kd, kt32, dst)                                             \
  do {                                                                         \
    _Pragma("unroll")                                                          \
    for (int j = 0; j < 2; ++j) {                                              \
      const int cb = j * 8 + wave;                /* 0..15 */                  \
      const int srow = (cb * 64 + lane) >> 2;     /* 0..255 */                 \
      gload_lds16((G) + (size_t)srow * (Kd) + (kt32) * 32 + kp,                \
                  (dst) + cb * 512);                                           \
    }                                                                          \
  } while (0)
#define GSTAGE_B(G, Kd, kt32, dst)                                             \
  do {                                                                         \
    const int cb = wave;                          /* 0..7 */                   \
    const int srow = (cb * 64 + lane) >> 2;       /* 0..127 */                 \
    gload_lds16((G) + (size_t)srow * (Kd) + (kt32) * 32 + kp,                  \
                (dst) + cb * 512);                                             \
  } while (0)

// ---------------------------------------------------------------------------
// bf16 MFMA GEMM, TRIPLE-buffered BK=32 counted-vmcnt pipeline (R23-proven).
// 256x128 tile, 512 thr = 8 waves.  LDS 72 KB -> 2 blocks/CU.  Natural block
// order (R27 showed XCD swizzle doubles FETCH on this grid).  setprio kept.
// Used for the Wo GEMM (fp32 out), where only 128 256^2-blocks would exist.
// ---------------------------------------------------------------------------
template<bool BF16OUT>
__global__ __launch_bounds__(512) void gemm_mfma(
    const ushort_t* __restrict__ A, const ushort_t* __restrict__ BT,
    void* __restrict__ CV, int N, int K) {
  __shared__ ushort_t Ah[3][256 * 32];   // 48 KB
  __shared__ ushort_t Bh[3][128 * 32];   // 24 KB
  const int tid = threadIdx.x;
  const int wave = tid >> 6, lane = tid & 63;
  const size_t brow = (size_t)blockIdx.y * 256;
  const size_t bcol = (size_t)blockIdx.x * 128;
  const int wr = (wave >> 1) * 64, wc = (wave & 1) * 64;
  const int frow = lane & 15;
  const int fko  = ((lane >> 4) ^ (frow & 3)) * 8;          // swizzled read k-off
  const int kp   = (((lane & 3) ^ ((lane >> 2) & 3)) * 8);  // inverse-swz src k-off

  f32x4 acc[4][4];
#pragma unroll
  for (int m = 0; m < 4; ++m)
#pragma unroll
    for (int n = 0; n < 4; ++n) acc[m][n] = f32x4{0.f, 0.f, 0.f, 0.f};

  const ushort_t* Ag = A + brow * K;
  const ushort_t* Bg = BT + bcol * K;
  const int NT = K >> 5;                 // K-tiles of 32

  GSTAGE_A(Ag, K, 0, Ah[0]);
  GSTAGE_B(Bg, K, 0, Bh[0]);
  GSTAGE_A(Ag, K, 1, Ah[1]);
  GSTAGE_B(Bg, K, 1, Bh[1]);
  asm volatile("s_waitcnt vmcnt(3)" ::: "memory");
  __builtin_amdgcn_s_barrier();

  int rb = 0, sb = 2;                    // read buf, stage buf
  bf16x8 af[4], bfr[4];
  for (int kt = 0; kt < NT; ++kt) {
#pragma unroll
    for (int m = 0; m < 4; ++m)
      af[m] = *(const bf16x8*)(&Ah[rb][(wr + m * 16 + frow) * 32 + fko]);
#pragma unroll
    for (int n = 0; n < 4; ++n)
      bfr[n] = *(const bf16x8*)(&Bh[rb][(wc + n * 16 + frow) * 32 + fko]);
    if (kt + 2 < NT) {
      GSTAGE_A(Ag, K, kt + 2, Ah[sb]);
      GSTAGE_B(Bg, K, kt + 2, Bh[sb]);
    }
    __builtin_amdgcn_s_setprio(1);
#pragma unroll
    for (int m = 0; m < 4; ++m)
#pragma unroll
      for (int n = 0; n < 4; ++n) acc[m][n] = mfma16(af[m], bfr[n], acc[m][n]);
    __builtin_amdgcn_s_setprio(0);
    if (kt + 1 < NT) {
      if (kt + 2 < NT) asm volatile("s_waitcnt vmcnt(3)" ::: "memory");
      else             asm volatile("s_waitcnt vmcnt(0)" ::: "memory");
      __builtin_amdgcn_s_barrier();
    }
    rb = (rb == 2) ? 0 : rb + 1;
    sb = (sb == 2) ? 0 : sb + 1;
  }

  const int crow = (lane >> 4) * 4;
  const int ccol = lane & 15;
#pragma unroll
  for (int m = 0; m < 4; ++m)
#pragma unroll
    for (int n = 0; n < 4; ++n) {
      const size_t base = (brow + wr + m * 16 + crow) * (size_t)N + (bcol + wc + n * 16 + ccol);
      if constexpr (BF16OUT) {
        ushort_t* Out = (ushort_t*)CV;
#pragma unroll
        for (int j = 0; j < 4; ++j) Out[base + (size_t)j * N] = f2bf(acc[m][n][j]);
      } else {
        float* Out = (float*)CV;
#pragma unroll
        for (int j = 0; j < 4; ++j) Out[base + (size_t)j * N] = acc[m][n][j];
      }
    }
}

// ---------------------------------------------------------------------------
// R28: 256x256-tile variant for the qkvg GEMM.  Same triple-buffered BK=32
// counted-vmcnt FIFO as above (4 staging loads/tile -> vmcnt(4)), but
// 32 MFMA per barrier-pair per wave (2x amortization).  8 waves as 2Mx4N,
// per-wave output 128x64.  LDS 96 KB -> 1 block/CU.  K-order per
// accumulator identical to the 256x128 kernel -> bit-identical output.
// ---------------------------------------------------------------------------
#define GSTAGE256(G, Kd, kt32, dst)                                            \
  do {                                                                         \
    _Pragma("unroll")                                                          \
    for (int j = 0; j < 2; ++j) {                                              \
      const int cb = j * 8 + wave;                /* 0..15 */                  \
      const int srow = (cb * 64 + lane) >> 2;     /* 0..255 */                 \
      gload_lds16((G) + (size_t)srow * (Kd) + (kt32) * 32 + kp,                \
                  (dst) + cb * 512);                                           \
    }                                                                          \
  } while (0)

__global__ __launch_bounds__(512) void gemm_mfma256(
    const ushort_t* __restrict__ A, const ushort_t* __restrict__ BT,
    ushort_t* __restrict__ C, int N, int K) {
  __shared__ ushort_t Ah[3][256 * 32];   // 48 KB
  __shared__ ushort_t Bh[3][256 * 32];   // 48 KB
  const int tid = threadIdx.x;
  const int wave = tid >> 6, lane = tid & 63;
  const size_t brow = (size_t)blockIdx.y * 256;
  const size_t bcol = (size_t)blockIdx.x * 256;
  const int wrow = (wave >> 2) * 128;    // 2 M-waves
  const int wcol = (wave & 3) * 64;      // 4 N-waves
  const int frow = lane & 15;
  const int fko  = ((lane >> 4) ^ (frow & 3)) * 8;
  const int kp   = (((lane & 3) ^ ((lane >> 2) & 3)) * 8);

  f32x4 acc[8][4];
#pragma unroll
  for (int m = 0; m < 8; ++m)
#pragma unroll
    for (int n = 0; n < 4; ++n) acc[m][n] = f32x4{0.f, 0.f, 0.f, 0.f};

  const ushort_t* Ag = A + brow * K;
  const ushort_t* Bg = BT + bcol * K;
  const int NT = K >> 5;                 // K-tiles of 32

  // prologue: stage tiles 0,1 (4 loads each); wait first 4 -> tile 0 done.
  GSTAGE256(Ag, K, 0, Ah[0]);
  GSTAGE256(Bg, K, 0, Bh[0]);
  GSTAGE256(Ag, K, 1, Ah[1]);
  GSTAGE256(Bg, K, 1, Bh[1]);
  asm volatile("s_waitcnt vmcnt(4)" ::: "memory");
  __builtin_amdgcn_s_barrier();

  int rb = 0, sb = 2;                    // read buf, stage buf
  bf16x8 af[8], bfr[4];
  for (int kt = 0; kt < NT; ++kt) {
    // ---- ds-read fragments from buf rb (guaranteed by prior vmcnt+barrier)
#pragma unroll
    for (int m = 0; m < 8; ++m)
      af[m] = *(const bf16x8*)(&Ah[rb][(wrow + m * 16 + frow) * 32 + fko]);
#pragma unroll
    for (int n = 0; n < 4; ++n)
      bfr[n] = *(const bf16x8*)(&Bh[rb][(wcol + n * 16 + frow) * 32 + fko]);
    // ---- stage tile kt+2 into buf sb (!= rb, != next)
    if (kt + 2 < NT) {
      GSTAGE256(Ag, K, kt + 2, Ah[sb]);
      GSTAGE256(Bg, K, kt + 2, Bh[sb]);
    }
    // ---- 32 MFMA (2x the 256x128 kernel's per-barrier amortization)
    __builtin_amdgcn_s_setprio(1);
#pragma unroll
    for (int m = 0; m < 8; ++m)
#pragma unroll
      for (int n = 0; n < 4; ++n) acc[m][n] = mfma16(af[m], bfr[n], acc[m][n]);
    __builtin_amdgcn_s_setprio(0);
    // ---- retire tile kt+1 before all waves cross -> next reads safe
    if (kt + 1 < NT) {
      if (kt + 2 < NT) asm volatile("s_waitcnt vmcnt(4)" ::: "memory");
      else             asm volatile("s_waitcnt vmcnt(0)" ::: "memory");
      __builtin_amdgcn_s_barrier();
    }
    rb = (rb == 2) ? 0 : rb + 1;
    sb = (sb == 2) ? 0 : sb + 1;
  }

  const int crow = (lane >> 4) * 4;
  const int ccol = lane & 15;
#pragma unroll
  for (int m = 0; m < 8; ++m)
#pragma unroll
    for (int n = 0; n < 4; ++n) {
      const size_t base = (brow + wrow + m * 16 + crow) * (size_t)N + (bcol + wcol + n * 16 + ccol);
#pragma unroll
      for (int j = 0; j < 4; ++j) C[base + (size_t)j * N] = f2bf(acc[m][n][j]);
    }
}

// ---------------------------------------------------------------------------
// Fused prologue: 5 weight transposes + {x->bf16 AND gk} per row.
// ---------------------------------------------------------------------------
__global__ __launch_bounds__(256) void prep_all(
    const float* __restrict__ Wq, const float* __restrict__ Wk,
    const float* __restrict__ Wv, const float* __restrict__ Wg,
    const float* __restrict__ Wo, const float* __restrict__ x,
    const float* __restrict__ Wgk, const float* __restrict__ bgk,
    ushort_t* __restrict__ WqT, ushort_t* __restrict__ WkT,
    ushort_t* __restrict__ WvT, ushort_t* __restrict__ WgT,
    ushort_t* __restrict__ WoT, ushort_t* __restrict__ xb,
    float* __restrict__ gkbuf) {
  __shared__ float tile[32][33];
  __shared__ float4 red4[256];
  const int blk = blockIdx.x;
  const int tid = threadIdx.x;
  if (blk >= 8192) {   // x -> bf16 + gk: one row (1024 floats) per block
    const int row = blk - 8192;
    const size_t i = ((size_t)row * 1024) + tid * 4;
    float4 v = *(const float4*)(x + i);
    ushort4 r;
    r.x = f2bf(v.x); r.y = f2bf(v.y); r.z = f2bf(v.z); r.w = f2bf(v.w);
    *(ushort4*)(xb + i) = r;
    float4 p = {0.f, 0.f, 0.f, 0.f};
    const float4* wg4 = (const float4*)Wgk;   // [1024] rows of 4
    const float xv[4] = {v.x, v.y, v.z, v.w};
#pragma unroll
    for (int j = 0; j < 4; ++j) {
      float4 wg = wg4[tid * 4 + j];
      p.x += xv[j] * wg.x; p.y += xv[j] * wg.y;
      p.z += xv[j] * wg.z; p.w += xv[j] * wg.w;
    }
    red4[tid] = p;
    __syncthreads();
    for (int off2 = 128; off2; off2 >>= 1) {
      if (tid < off2) {
        float4 a = red4[tid], b4 = red4[tid + off2];
        a.x += b4.x; a.y += b4.y; a.z += b4.z; a.w += b4.w;
        red4[tid] = a;
      }
      __syncthreads();
    }
    if (tid < 4) {
      const float z  = (&red4[0].x)[tid] + bgk[tid];
      const float ls = fminf(z, 0.f) - log1pf(expf(-fabsf(z)));
      const int b = row >> 11, n = row & 2047;
      gkbuf[((size_t)(b * NH_ + tid)) * N_ + n] = ls * (1.0f / 16.0f);
    }
    return;
  }
  const float* W; ushort_t* WT; int K, Nn, gxw, local;
  if (blk < 1024)      { W = Wq; WT = WqT; K = 1024; Nn = 1024; gxw = 32; local = blk; }
  else if (blk < 2048) { W = Wk; WT = WkT; K = 1024; Nn = 1024; gxw = 32; local = blk - 1024; }
  else if (blk < 4096) { W = Wv; WT = WvT; K = 1024; Nn = 2048; gxw = 64; local = blk - 2048; }
  else if (blk < 6144) { W = Wg; WT = WgT; K = 1024; Nn = 2048; gxw = 64; local = blk - 4096; }
  else                 { W = Wo; WT = WoT; K = 2048; Nn = 1024; gxw = 32; local = blk - 6144; }
  const int n0 = (local % gxw) * 32, k0 = (local / gxw) * 32;
  const int tx = tid & 31, ty = tid >> 5;
#pragma unroll
  for (int i = 0; i < 32; i += 8)
    tile[ty + i][tx] = W[(size_t)(k0 + ty + i) * Nn + n0 + tx];
  __syncthreads();
#pragma unroll
  for (int i = 0; i < 32; i += 8)
    WT[(size_t)(n0 + ty + i) * K + k0 + tx] = f2bf(tile[tx][ty + i]);
}

// ---------------------------------------------------------------------------
// per-(bh,chunk) inclusive cumsum of gk
// ---------------------------------------------------------------------------
__global__ __launch_bounds__(64) void cumsum_kernel(const float* __restrict__ gkbuf,
                                                    float* __restrict__ gcbuf) {
  const int bh = blockIdx.x;
  const int c  = threadIdx.x;
  if (c < NC_) {
    const size_t base = (size_t)bh * N_ + c * C_;
    float acc = 0.f;
    for (int t = 0; t < C_; ++t) { acc += gkbuf[base + t]; gcbuf[base + t] = acc; }
  }
}

// ---------------------------------------------------------------------------
// Fused post-qkv stage (reads fused qkvg16 [8192][6144]):
//   [0,512) a_mfma | [512,1024) pack_kT | [1024,2048) pack_vT |
//   [2048,6144) pack_q16
// ---------------------------------------------------------------------------
__global__ __launch_bounds__(256) void post_qkv(
    const ushort_t* __restrict__ qkvg16, const float* __restrict__ gc,
    ushort_t* __restrict__ Abuf, ushort_t* __restrict__ kT,
    ushort_t* __restrict__ vT, ushort_t* __restrict__ q16) {
  __shared__ __align__(16) char smem[256 * 68 * 2 + 256];
  const int gblk = blockIdx.x;
  const int tid = threadIdx.x;

  if (gblk < 512) {               // ---------------- a_mfma
    const int blk = gblk;
    const int bh  = blk >> 5, c = blk & 31;
    const int b   = bh >> 2, h = bh & 3;
    float* gcs = (float*)smem;    // [64]
    const int w = tid >> 6, l = tid & 63;
    const int frow = l & 15, fgrp = l >> 4;
    if (tid < 64) gcs[tid] = gc[(size_t)bh * N_ + c * C_ + tid];
    __syncthreads();

    const size_t rbase = (size_t)(b * N_ + c * C_);
    bf16x8 aqr[8];
#pragma unroll
    for (int kk = 0; kk < 8; ++kk)
      aqr[kk] = *(const bf16x8*)(qkvg16 + (rbase + w * 16 + frow) * QW_ +
                                 h * 256 + kk * 32 + fgrp * 8);

    ushort_t* ab = Abuf + (size_t)blk * 4096;
    const float scl = 0.0625f;
#pragma unroll
    for (int n = 0; n < 4; ++n) {
      f32x4 acc = f32x4{0.f, 0.f, 0.f, 0.f};
#pragma unroll
      for (int kk = 0; kk < 8; ++kk) {
        bf16x8 bk = *(const bf16x8*)(qkvg16 + (rbase + n * 16 + frow) * QW_ +
                                     1024 + h * 256 + kk * 32 + fgrp * 8);
        acc = mfma16(aqr[kk], bk, acc);
      }
      const int s = n * 16 + frow;
      const float gcss = gcs[s];
#pragma unroll
      for (int j = 0; j < 4; ++j) {
        const int t = w * 16 + fgrp * 4 + j;
        const float val = (s <= t) ? acc[j] * scl * expf(gcs[t] - gcss) : 0.f;
        ab[(size_t)t * 64 + s] = f2bf(val);
      }
    }
  } else if (gblk < 1024) {       // ---------------- pack_kT
    const int blk = gblk - 512;
    const int bh = blk >> 5, c = blk & 31;
    const int b = bh >> 2, h = bh & 3;
    ushort_t (*kl)[68] = (ushort_t (*)[68])smem;           // [256][68]
    float* fk = (float*)(smem + 256 * 68 * 2);             // [64]
    if (tid < 64) {
      const float gct = gc[(size_t)bh * N_ + c * C_ + tid];
      const float gt  = gc[(size_t)bh * N_ + c * C_ + 63];
      fk[tid] = expf(gt - gct);
    }
    __syncthreads();
    const ushort_t* kb = qkvg16 + (size_t)(b * N_ + c * C_) * QW_ + 1024 + h * 256;
    for (int it = 0; it < 8; ++it) {
      const int e = it * 256 + tid;
      const int t = e >> 5, d8 = (e & 31) * 8;
      bf16x8 kv = *(const bf16x8*)(kb + (size_t)t * QW_ + d8);
      const float f = fk[t];
#pragma unroll
      for (int j = 0; j < 8; ++j) kl[d8 + j][t] = f2bf(bf2f((ushort_t)kv[j]) * f);
    }
    __syncthreads();
    ushort_t* out = kT + (size_t)blk * 16384;
    for (int it = 0; it < 8; ++it) {
      const int e = it * 256 + tid;
      const int d = e >> 3, t8 = (e & 7) * 8;
      ushort4 lo, hi;
      lo.x = kl[d][t8 + 0]; lo.y = kl[d][t8 + 1]; lo.z = kl[d][t8 + 2]; lo.w = kl[d][t8 + 3];
      hi.x = kl[d][t8 + 4]; hi.y = kl[d][t8 + 5]; hi.z = kl[d][t8 + 6]; hi.w = kl[d][t8 + 7];
      *(ushort4*)(out + (size_t)d * 64 + t8)     = lo;
      *(ushort4*)(out + (size_t)d * 64 + t8 + 4) = hi;
    }
  } else if (gblk < 2048) {       // ---------------- pack_vT
    const int blk = gblk - 1024;
    const int eh = blk & 1, c = (blk >> 1) & 31, bh = blk >> 6;
    const int b = bh >> 2, h = bh & 3;
    ushort_t (*vl)[68] = (ushort_t (*)[68])smem;           // [256][68]
    const ushort_t* vb = qkvg16 + (size_t)(b * N_ + c * C_) * QW_ + 2048 + h * 512 + eh * 256;
    for (int it = 0; it < 8; ++it) {
      const int e = it * 256 + tid;
      const int s = e >> 5, c8 = (e & 31) * 8;
      bf16x8 val = *(const bf16x8*)(vb + (size_t)s * QW_ + c8);
#pragma unroll
      for (int j = 0; j < 8; ++j) vl[c8 + j][s] = (ushort_t)val[j];
    }
    __syncthreads();
    ushort_t* out = vT + (size_t)bh * 512 * 2048 + (size_t)(eh * 256) * 2048 + c * C_;
    for (int it = 0; it < 8; ++it) {
      const int e = it * 256 + tid;
      const int r = e >> 3, t8 = (e & 7) * 8;
      ushort4 lo, hi;
      lo.x = vl[r][t8 + 0]; lo.y = vl[r][t8 + 1]; lo.z = vl[r][t8 + 2]; lo.w = vl[r][t8 + 3];
      hi.x = vl[r][t8 + 4]; hi.y = vl[r][t8 + 5]; hi.z = vl[r][t8 + 6]; hi.w = vl[r][t8 + 7];
      *(ushort4*)(out + (size_t)r * 2048 + t8)     = lo;
      *(ushort4*)(out + (size_t)r * 2048 + t8 + 4) = hi;
    }
  } else {                        // ---------------- pack_q16
    const size_t i8 = ((size_t)(gblk - 2048) * 256 + tid) * 8;   // < M*1024
    const int row = (int)(i8 >> 10);
    const int col = (int)(i8 & 1023);
    const int b = row >> 11, n = row & 2047;
    const int h = col >> 8;
    const float f = 0.0625f * expf(gc[(size_t)(b * NH_ + h) * N_ + n]);
    bf16x8 v = *(const bf16x8*)(qkvg16 + (size_t)row * QW_ + col);
    ushort_t r[8];
#pragma unroll
    for (int j = 0; j < 8; ++j) r[j] = f2bf(bf2f((ushort_t)v[j]) * f);
    *(bf16x8*)(q16 + i8) = *(bf16x8*)r;
  }
}

// ---------------------------------------------------------------------------
// Segmented MFMA chunk scan, EBLK=64, cross-barrier prefetch of aq+bv+aa.
// SINGLE S^T buffer (33.8 KB LDS -> 4 WG/CU) with 2 barriers/chunk.
// grid = (16 bh, 8 vblk, 4 seg), wgid%8 = bh%8 (XCD affinity).
// ---------------------------------------------------------------------------
#define LOAD_AQ(cc, dst)                                                       \
  do {                                                                         \
    _Pragma("unroll")                                                          \
    for (int kk = 0; kk < 8; ++kk)                                             \
      dst[kk] = *(const bf16x8*)(qbase + (size_t)((cc) * C_ + w * 16 + frow) * 1024 + \
                                 kk * 32 + fgrp * 8);                          \
  } while (0)
#define LOAD_BV(cc, dst)                                                       \
  do {                                                                         \
    _Pragma("unroll")                                                          \
    for (int kt = 0; kt < 2; ++kt)                                             \
      _Pragma("unroll")                                                        \
      for (int n = 0; n < 4; ++n)                                              \
        dst[kt][n] = *(const bf16x8*)(vbase + (size_t)(n * 16 + frow) * 2048 + \
                                      (cc) * C_ + kt * 32 + fgrp * 8);         \
  } while (0)
#define LOAD_AA(cc, dst)                                                       \
  do {                                                                         \
    _Pragma("unroll")                                                          \
    for (int kt = 0; kt < 2; ++kt)                                             \
      dst[kt] = *(const bf16x8*)(abase + (size_t)(cc) * 4096 +                 \
                                 (w * 16 + frow) * 64 + kt * 32 + fgrp * 8);   \
  } while (0)

__global__ __launch_bounds__(256) void scan_mfma(
    const ushort_t* __restrict__ q16,   // [8192][1024] pre-scaled bf16
    const ushort_t* __restrict__ kT,    // [bh][c][256][64] decayed bf16
    const ushort_t* __restrict__ vT,    // [bh][512][2048] bf16
    const ushort_t* __restrict__ ab,    // [bh*32+c][64][64] bf16
    const float*    __restrict__ gc,
    ushort_t* __restrict__ o,           // [8192][2048] bf16 (intra-segment part)
    float*    __restrict__ U) {         // [bh][seg 0..2][256][512] fp32
  const int bh = blockIdx.x, vblk = blockIdx.y, sg = blockIdx.z;
  const int b = bh >> 2, h = bh & 3;
  const int e0 = vblk * 64;
  const int c0 = sg * CSEG_;
  __shared__ ushort_t sbt[64][264];     // S^T bf16 single buffer (33.8 KB)
  __shared__ float egts[NC_];
  const int tid = threadIdx.x;
  const int w = tid >> 6, l = tid & 63;
  const int frow = l & 15, fgrp = l >> 4;

  for (int i = tid; i < 64 * 264 / 2; i += 256) ((unsigned*)&sbt[0][0])[i] = 0u;
  if (tid < NC_) egts[tid] = expf(gc[(size_t)bh * N_ + tid * C_ + 63]);
  f32x4 s_acc[4][4];
#pragma unroll
  for (int sm = 0; sm < 4; ++sm)
#pragma unroll
    for (int sn = 0; sn < 4; ++sn) s_acc[sm][sn] = f32x4{0.f, 0.f, 0.f, 0.f};
  __syncthreads();

  const ushort_t* qbase = q16 + (size_t)(b * N_) * 1024 + h * 256;
  const ushort_t* kbase = kT + (size_t)bh * NC_ * 16384;
  const ushort_t* vbase = vT + (size_t)bh * 512 * 2048 + (size_t)e0 * 2048;
  const ushort_t* abase = ab + (size_t)bh * NC_ * 4096;
  ushort_t*       obase = o + (size_t)(b * N_) * 2048 + h * 512 + e0;

  bf16x8 aqP[8], bvP[2][4], aaP[2];
  LOAD_AQ(c0, aqP);
  LOAD_BV(c0, bvP);
  LOAD_AA(c0, aaP);

  for (int c = c0; c < c0 + CSEG_; ++c) {
    const float egt = egts[c];

    // consume prefetched operands (SSA copies)
    bf16x8 aq[8], bv[2][4], aa[2];
#pragma unroll
    for (int kk = 0; kk < 8; ++kk) aq[kk] = aqP[kk];
#pragma unroll
    for (int kt = 0; kt < 2; ++kt) {
      aa[kt] = aaP[kt];
#pragma unroll
      for (int n = 0; n < 4; ++n) bv[kt][n] = bvP[kt][n];
    }

    // ---- o = A@v + q@Sb   (wave w: o rows w*16..+16, cols e0..e0+64)
#pragma unroll
    for (int n = 0; n < 4; ++n) {
      f32x4 oa = f32x4{0.f, 0.f, 0.f, 0.f};
#pragma unroll
      for (int kt = 0; kt < 2; ++kt) oa = mfma16(aa[kt], bv[kt][n], oa);
#pragma unroll
      for (int kk = 0; kk < 8; ++kk) {
        bf16x8 bs = *(const bf16x8*)(&sbt[n * 16 + frow][kk * 32 + fgrp * 8]);
        oa = mfma16(aq[kk], bs, oa);
      }
#pragma unroll
      for (int j = 0; j < 4; ++j)
        obase[(size_t)(c * C_ + w * 16 + fgrp * 4 + j) * 2048 + n * 16 + frow] = f2bf(oa[j]);
    }

    // ---- S = e^gt * S + kT @ v   (wave w: d rows w*64..+64, all 64 e)
#pragma unroll
    for (int sm = 0; sm < 4; ++sm)
#pragma unroll
      for (int sn = 0; sn < 4; ++sn)
#pragma unroll
        for (int j = 0; j < 4; ++j) s_acc[sm][sn][j] *= egt;
#pragma unroll
    for (int kt = 0; kt < 2; ++kt)
#pragma unroll
      for (int sm = 0; sm < 4; ++sm) {
        bf16x8 ak = *(const bf16x8*)(kbase + (size_t)c * 16384 +
                                     (size_t)(w * 64 + sm * 16 + frow) * 64 + kt * 32 + fgrp * 8);
#pragma unroll
        for (int sn = 0; sn < 4; ++sn)
          s_acc[sm][sn] = mfma16(ak, bv[kt][sn], s_acc[sm][sn]);
      }

    // ---- prefetch next chunk's operands (issued before barriers; used after)
    if (c + 1 < c0 + CSEG_) {
      LOAD_AQ(c + 1, aqP);
      LOAD_BV(c + 1, bvP);
      LOAD_AA(c + 1, aaP);
    }

    __syncthreads();   // all waves' sbt reads of this chunk complete

    // ---- publish S^T bf16 into the (single) buffer
#pragma unroll
    for (int sm = 0; sm < 4; ++sm)
#pragma unroll
      for (int sn = 0; sn < 4; ++sn) {
        ushort4 pk;
        pk.x = f2bf(s_acc[sm][sn][0]); pk.y = f2bf(s_acc[sm][sn][1]);
        pk.z = f2bf(s_acc[sm][sn][2]); pk.w = f2bf(s_acc[sm][sn][3]);
        *(ushort4*)&sbt[sn * 16 + frow][w * 64 + sm * 16 + fgrp * 4] = pk;
      }
    __syncthreads();   // publish visible; next chunk reads sbt
  }

  // ---- write segment-final state U (fp32) for segments 0..2
  if (sg < NSEG_ - 1) {
    float* ub = U + (size_t)(bh * (NSEG_ - 1) + sg) * 256 * 512;
#pragma unroll
    for (int sm = 0; sm < 4; ++sm)
#pragma unroll
      for (int sn = 0; sn < 4; ++sn)
#pragma unroll
        for (int j = 0; j < 4; ++j)
          ub[(size_t)(w * 64 + sm * 16 + fgrp * 4 + j) * 512 + e0 + sn * 16 + frow] =
              s_acc[sm][sn][j];
  }
}

// ---------------------------------------------------------------------------
// Cross-segment correction with inlined combine (fp32 recurrence from U).
// o[t] += D_c * (q16[t] @ S_in(seg)).  grid (16 bh, 32 vb, 3), seg = z+1.
// ---------------------------------------------------------------------------
__global__ __launch_bounds__(256) void correct_kernel(
    const ushort_t* __restrict__ q16, const float* __restrict__ U,
    const float* __restrict__ gc, ushort_t* __restrict__ o) {
  const int bh = blockIdx.x, vb = blockIdx.y, z = blockIdx.z;
  const int sg = z + 1, c0 = sg * CSEG_;
  const int b = bh >> 2, h = bh & 3;
  __shared__ ushort_t sT[16][264];
  __shared__ float dseg[CSEG_];
  const int tid = threadIdx.x;
  const int w = tid >> 6, l = tid & 63;
  const int frow = l & 15, fgrp = l >> 4;

  {  // inlined combine: thread covers e = tid>>4, d = (tid&15)*16 .. +16
    const int e = tid >> 4, dbase = (tid & 15) * 16;
    float E[NSEG_ - 1];
#pragma unroll
    for (int s = 0; s < NSEG_ - 1; ++s) {
      float gsum = 0.f;
      for (int c = s * CSEG_; c < (s + 1) * CSEG_; ++c)
        gsum += gc[(size_t)bh * N_ + c * C_ + 63];
      E[s] = expf(gsum);
    }
#pragma unroll
    for (int d = 0; d < 16; ++d) {
      float S = 0.f;
      for (int s = 0; s <= z; ++s)
        S = E[s] * S + U[(size_t)(bh * (NSEG_ - 1) + s) * 256 * 512 +
                         (size_t)(dbase + d) * 512 + vb * 16 + e];
      sT[e][dbase + d] = f2bf(S);
    }
  }
  if (tid < CSEG_) {
    float s = 0.f;
    for (int i = 0; i < tid; ++i) s += gc[(size_t)bh * N_ + (c0 + i) * C_ + 63];
    dseg[tid] = expf(s);
  }
  __syncthreads();

  const ushort_t* qbase = q16 + (size_t)(b * N_) * 1024 + h * 256;
  ushort_t* obase = o + (size_t)(b * N_) * 2048 + h * 512 + vb * 16;

  for (int c = c0; c < c0 + CSEG_; ++c) {
    const float D = dseg[c - c0];
    f32x4 oa = f32x4{0.f, 0.f, 0.f, 0.f};
#pragma unroll
    for (int kk = 0; kk < 8; ++kk) {
      bf16x8 aq = *(const bf16x8*)(qbase + (size_t)(c * C_ + w * 16 + frow) * 1024 + kk * 32 + fgrp * 8);
      bf16x8 bs = *(const bf16x8*)(&sT[frow][kk * 32 + fgrp * 8]);
      oa = mfma16(aq, bs, oa);
    }
#pragma unroll
    for (int j = 0; j < 4; ++j) {
      const size_t idx = (size_t)(c * C_ + w * 16 + fgrp * 4 + j) * 2048 + frow;
      obase[idx] = f2bf(bf2f(obase[idx]) + D * oa[j]);
    }
  }
}

// ---------------------------------------------------------------------------
// ob(bf16) <- RMSNorm(o bf16)*gnorm_w * swish(g), g from fused qkvg16
// ---------------------------------------------------------------------------
__global__ __launch_bounds__(256) void normgate_kernel(const ushort_t* __restrict__ o,
    const ushort_t* __restrict__ qkvg16, const float* __restrict__ w,
    ushort_t* __restrict__ ob) {
  const int blk = blockIdx.x;          // row*NH + h
  const int row = blk >> 2, h = blk & 3;
  const size_t base = (size_t)blk * DV_;
  const size_t gbase = (size_t)row * QW_ + 4096 + h * DV_;
  const int tid = threadIdx.x;
  __shared__ float red2[256];
  const float v0 = bf2f(o[base + tid]), v1 = bf2f(o[base + tid + 256]);
  red2[tid] = v0 * v0 + v1 * v1;
  __syncthreads();
  for (int off = 128; off; off >>= 1) {
    if (tid < off) red2[tid] += red2[tid + off];
    __syncthreads();
  }
  const float rms = rsqrtf(red2[0] * (1.0f / 512.0f) + 1e-5f);
  const float g0 = bf2f(qkvg16[gbase + tid]), g1 = bf2f(qkvg16[gbase + tid + 256]);
  const float sw0 = g0 / (1.f + expf(-g0));
  const float sw1 = g1 / (1.f + expf(-g1));
  ob[base + tid]       = f2bf(v0 * rms * w[tid] * sw0);
  ob[base + tid + 256] = f2bf(v1 * rms * w[tid + 256] * sw1);
}

// ---------------------------------------------------------------------------
// Workspace (float units), total 59,834,368 fl = 228.25 MiB (R7-proven size):
//   gk 32K | gc 32K | qkvg16 25.17M | o 8.39M | ab16 1.05M |
//   q16 4.19M | kTp 4.19M | vTp 8.39M | xb 4.19M | W*T 4.19M
// Aliases (time-disjoint, verified against launch order):
//   U  (6.29M fp32) = xb+WqT+WkT+WvT  [all dead after fused qkvg GEMM;
//                                      WoT (beyond) untouched]
//   ob (8.39M fl)   = vTp             [dead after scan]
// ---------------------------------------------------------------------------
extern "C" void kernel_launch(void* const* d_in, const int* in_sizes, int n_in,
                              void* d_out, int out_size, void* d_ws, size_t ws_size,
                              hipStream_t stream) {
  (void)in_sizes; (void)n_in; (void)out_size; (void)ws_size;
  const float* x    = (const float*)d_in[0];
  const float* Wq   = (const float*)d_in[1];
  const float* Wk   = (const float*)d_in[2];
  const float* Wv   = (const float*)d_in[3];
  const float* Wg   = (const float*)d_in[4];
  const float* Wgk  = (const float*)d_in[5];
  const float* bgk  = (const float*)d_in[6];
  const float* Wo   = (const float*)d_in[7];
  const float* gw   = (const float*)d_in[8];

  float* ws = (float*)d_ws;
  size_t off = 0;
  float* gk = ws + off; off += (size_t)16 * N_;
  float* gc = ws + off; off += (size_t)16 * N_;
  ushort_t* qkvg16 = (ushort_t*)(ws + off); off += (size_t)M_ * QW_ / 2;
  ushort_t* o    = (ushort_t*)(ws + off); off += (size_t)M_ * 2048 / 2;
  ushort_t* ab16 = (ushort_t*)(ws + off); off += (size_t)16 * NC_ * 4096 / 2;
  ushort_t* q16  = (ushort_t*)(ws + off); off += (size_t)M_ * 1024 / 2;
  ushort_t* kTp  = (ushort_t*)(ws + off); off += (size_t)16 * NC_ * 16384 / 2;
  ushort_t* vTp  = (ushort_t*)(ws + off); size_t vTp_off = off; off += (size_t)16 * 512 * 2048 / 2;
  ushort_t* xb   = (ushort_t*)(ws + off); size_t xb_off = off; off += (size_t)M_ * HID_ / 2;
  ushort_t* WqT  = (ushort_t*)(ws + off); off += (size_t)1024 * 1024 / 2;
  ushort_t* WkT  = (ushort_t*)(ws + off); off += (size_t)1024 * 1024 / 2;
  ushort_t* WvT  = (ushort_t*)(ws + off); off += (size_t)2048 * 1024 / 2;
  ushort_t* WgT  = (ushort_t*)(ws + off); off += (size_t)2048 * 1024 / 2;
  ushort_t* WoT  = (ushort_t*)(ws + off); off += (size_t)1024 * 2048 / 2;
  // time-disjoint aliases (see table above)
  float*    U    = ws + xb_off;                            // 6.29M fl over xb+W[qkv]T
  ushort_t* ob   = (ushort_t*)(ws + vTp_off);              // 8.39M fl over vTp

  dim3 thr(256);
  prep_all<<<16384, thr, 0, stream>>>(Wq, Wk, Wv, Wg, Wo, x, Wgk, bgk,
                                      WqT, WkT, WvT, WgT, WoT, xb, gk);

  // fused q|k|v|g projection: BT = [WqT;WkT;WvT;WgT] (contiguous), bf16 out
  gemm_mfma256<<<dim3(24, 32), 512, 0, stream>>>(xb, WqT, qkvg16, QW_, 1024);
  cumsum_kernel<<<16, 64, 0, stream>>>(gk, gc);
  post_qkv<<<6144, thr, 0, stream>>>(qkvg16, gc, ab16, kTp, vTp, q16);
  scan_mfma<<<dim3(16, 8, NSEG_), thr, 0, stream>>>(q16, kTp, vTp, ab16, gc, o, U);
  correct_kernel<<<dim3(16, 32, NSEG_ - 1), thr, 0, stream>>>(q16, U, gc, o);
  normgate_kernel<<<M_ * NH_, thr, 0, stream>>>(o, qkvg16, gw, ob);
  gemm_mfma<false><<<dim3(8, 32), 512, 0, stream>>>(ob, WoT, (float*)d_out, 1024, 2048);
}